// Round 1
// baseline (698.033 us; speedup 1.0000x reference)
//
#include <hip/hip_runtime.h>
#include <hip/hip_bf16.h>
#include <math.h>

#define NN 50000
#define EE 800000
#define FIN 256
#define HID 64
#define OUTD 64
#define H1 4
#define H2 1

// ---------------- CSR build ----------------

__global__ void hist_kernel(const int* __restrict__ dst, int* __restrict__ deg, int nE) {
    int e = blockIdx.x * 256 + threadIdx.x;
    if (e < nE) atomicAdd(&deg[dst[e]], 1);
}

__global__ void scan_block(const int* __restrict__ in, int* __restrict__ out,
                           int* __restrict__ bsums, int n) {
    __shared__ int sh[256];
    int i = blockIdx.x * 256 + threadIdx.x;
    int v = (i < n) ? in[i] : 0;
    sh[threadIdx.x] = v;
    __syncthreads();
    for (int off = 1; off < 256; off <<= 1) {
        int t = 0;
        if (threadIdx.x >= off) t = sh[threadIdx.x - off];
        __syncthreads();
        if (threadIdx.x >= off) sh[threadIdx.x] += t;
        __syncthreads();
    }
    if (i < n) out[i] = sh[threadIdx.x] - v;          // exclusive
    if (threadIdx.x == 255) bsums[blockIdx.x] = sh[255];
}

__global__ void scan_bsums(int* __restrict__ bsums, int nb) {
    __shared__ int sh[256];
    int v = (threadIdx.x < nb) ? bsums[threadIdx.x] : 0;
    sh[threadIdx.x] = v;
    __syncthreads();
    for (int off = 1; off < 256; off <<= 1) {
        int t = 0;
        if (threadIdx.x >= off) t = sh[threadIdx.x - off];
        __syncthreads();
        if (threadIdx.x >= off) sh[threadIdx.x] += t;
        __syncthreads();
    }
    if (threadIdx.x < nb) bsums[threadIdx.x] = sh[threadIdx.x] - v;  // exclusive
}

__global__ void add_offsets(int* __restrict__ out, const int* __restrict__ bsums,
                            int n, int Etot) {
    int i = blockIdx.x * 256 + threadIdx.x;
    if (i < n) out[i] += bsums[blockIdx.x];
    if (i == 0) out[n] = Etot;
}

__global__ void fill_csr(const int* __restrict__ src, const int* __restrict__ dst,
                         const int* __restrict__ rowptr, int* __restrict__ fillc,
                         int* __restrict__ csr_src, int nE) {
    int e = blockIdx.x * 256 + threadIdx.x;
    if (e < nE) {
        int d = dst[e];
        int pos = rowptr[d] + atomicAdd(&fillc[d], 1);
        csr_src[pos] = src[e];
    }
}

// ---------------- f32 tiled GEMM: C[M,Ncol] = A[M,K] @ B[K,Ncol] ----------------
// BM=64, BN=64, BK=16, 256 threads, 4x4 micro-tile. K %16==0, Ncol %4==0 assumed.

__global__ __launch_bounds__(256) void gemm_f32(
    const float* __restrict__ A, const float* __restrict__ B, float* __restrict__ C,
    int M, int Ncol, int K)
{
    __shared__ float As[16][64 + 1];
    __shared__ float Bs[16][64];
    int bm = blockIdx.y * 64, bn = blockIdx.x * 64;
    int tid = threadIdx.x;
    int tr = tid >> 4, tc = tid & 15;
    float acc[4][4] = {};

    for (int k0 = 0; k0 < K; k0 += 16) {
        // A tile load: row = bm + tid/4, 4 floats at col k0 + (tid%4)*4
        int ar = tid >> 2;
        int ac = (tid & 3) * 4;
        int arow = bm + ar;
        float4 av = make_float4(0.f, 0.f, 0.f, 0.f);
        if (arow < M) av = *(const float4*)(A + (size_t)arow * K + k0 + ac);
        As[ac + 0][ar] = av.x; As[ac + 1][ar] = av.y;
        As[ac + 2][ar] = av.z; As[ac + 3][ar] = av.w;
        // B tile load: row = k0 + tid/16, 4 floats at col bn + (tid%16)*4
        int br = tid >> 4;
        int bc = (tid & 15) * 4;
        float4 bv = make_float4(0.f, 0.f, 0.f, 0.f);
        if (bn + bc < Ncol) bv = *(const float4*)(B + (size_t)(k0 + br) * Ncol + bn + bc);
        *(float4*)&Bs[br][bc] = bv;
        __syncthreads();
#pragma unroll
        for (int kk = 0; kk < 16; ++kk) {
            float a0 = As[kk][tr * 4 + 0], a1 = As[kk][tr * 4 + 1];
            float a2 = As[kk][tr * 4 + 2], a3 = As[kk][tr * 4 + 3];
            float b0 = Bs[kk][tc * 4 + 0], b1 = Bs[kk][tc * 4 + 1];
            float b2 = Bs[kk][tc * 4 + 2], b3 = Bs[kk][tc * 4 + 3];
            acc[0][0] += a0 * b0; acc[0][1] += a0 * b1; acc[0][2] += a0 * b2; acc[0][3] += a0 * b3;
            acc[1][0] += a1 * b0; acc[1][1] += a1 * b1; acc[1][2] += a1 * b2; acc[1][3] += a1 * b3;
            acc[2][0] += a2 * b0; acc[2][1] += a2 * b1; acc[2][2] += a2 * b2; acc[2][3] += a2 * b3;
            acc[3][0] += a3 * b0; acc[3][1] += a3 * b1; acc[3][2] += a3 * b2; acc[3][3] += a3 * b3;
        }
        __syncthreads();
    }
#pragma unroll
    for (int i = 0; i < 4; ++i) {
        int row = bm + tr * 4 + i;
        if (row < M) {
            int col = bn + tc * 4;
            if (col < Ncol) {
                float4 v = make_float4(acc[i][0], acc[i][1], acc[i][2], acc[i][3]);
                *(float4*)(C + (size_t)row * Ncol + col) = v;
            }
        }
    }
}

// ---------------- per-node attention scores: el/er [N,H] ----------------
// one wave per node, lane = channel (D==64)

__global__ void node_scores(const float* __restrict__ z, const float* __restrict__ al,
                            const float* __restrict__ ar, float* __restrict__ el,
                            float* __restrict__ er, int Nn, int H) {
    int wave = (blockIdx.x * blockDim.x + threadIdx.x) >> 6;
    int lane = threadIdx.x & 63;
    if (wave >= Nn) return;
    for (int h = 0; h < H; ++h) {
        float zv = z[(size_t)wave * H * 64 + h * 64 + lane];
        float sl = zv * al[h * 64 + lane];
        float sr = zv * ar[h * 64 + lane];
#pragma unroll
        for (int off = 32; off; off >>= 1) {
            sl += __shfl_xor(sl, off);
            sr += __shfl_xor(sr, off);
        }
        if (lane == 0) {
            el[wave * H + h] = sl;
            er[wave * H + h] = sr;
        }
    }
}

// ---------------- edge-softmax + aggregation, one wave per (node, head) ----------------

__global__ void gat_aggregate(const float* __restrict__ z, const float* __restrict__ el,
                              const float* __restrict__ er, const int* __restrict__ rowptr,
                              const int* __restrict__ csr_src, const float* __restrict__ bias,
                              float* __restrict__ out, int Nn, int H, int do_elu)
{
    int gw = (blockIdx.x * blockDim.x + threadIdx.x) >> 6;
    int lane = threadIdx.x & 63;
    int n = gw / H;
    int h = gw - n * H;
    if (n >= Nn) return;
    int start = rowptr[n], end = rowptr[n + 1];
    float ern = er[n * H + h];

    // pass 1: max over incoming edges (lanes split edges)
    float m = -INFINITY;
    for (int i = start + lane; i < end; i += 64) {
        float e = el[csr_src[i] * H + h] + ern;
        e = e > 0.f ? e : 0.2f * e;
        m = fmaxf(m, e);
    }
#pragma unroll
    for (int off = 32; off; off >>= 1) m = fmaxf(m, __shfl_xor(m, off));

    // pass 2: sum of exp
    float ssum = 0.f;
    for (int i = start + lane; i < end; i += 64) {
        float e = el[csr_src[i] * H + h] + ern;
        e = e > 0.f ? e : 0.2f * e;
        ssum += __expf(e - m);
    }
#pragma unroll
    for (int off = 32; off; off >>= 1) ssum += __shfl_xor(ssum, off);
    float inv = ssum > 0.f ? 1.f / ssum : 0.f;

    // pass 3: weighted gather, lane = channel
    float acc = 0.f;
    for (int i = start; i < end; ++i) {
        int s = csr_src[i];
        float e = el[s * H + h] + ern;
        e = e > 0.f ? e : 0.2f * e;
        float a = __expf(e - m) * inv;
        acc += a * z[(size_t)s * H * 64 + h * 64 + lane];
    }
    acc += bias[h * 64 + lane];
    if (do_elu) acc = acc > 0.f ? acc : expm1f(acc);
    out[(size_t)n * H * 64 + h * 64 + lane] = acc;
}

// ---------------- launch ----------------

static inline size_t align_up(size_t x, size_t a) { return (x + a - 1) & ~(a - 1); }

extern "C" void kernel_launch(void* const* d_in, const int* in_sizes, int n_in,
                              void* d_out, int out_size, void* d_ws, size_t ws_size,
                              hipStream_t stream) {
    const float* x   = (const float*)d_in[0];
    const float* W1  = (const float*)d_in[1];
    const float* al1 = (const float*)d_in[2];
    const float* ar1 = (const float*)d_in[3];
    const float* b1  = (const float*)d_in[4];
    const float* W2  = (const float*)d_in[5];
    const float* al2 = (const float*)d_in[6];
    const float* ar2 = (const float*)d_in[7];
    const float* b2  = (const float*)d_in[8];
    const int*   src = (const int*)d_in[9];
    const int*   dst = (const int*)d_in[10];
    float* out = (float*)d_out;

    char* ws = (char*)d_ws;
    size_t off = 0;
    float* z1 = (float*)(ws + off); off = align_up(off + (size_t)NN * FIN * 4, 256);   // 51.2MB (reused as z2)
    float* h1 = (float*)(ws + off); off = align_up(off + (size_t)NN * FIN * 4, 256);   // 51.2MB
    float* el = (float*)(ws + off); off = align_up(off + (size_t)NN * H1 * 4, 256);
    float* er = (float*)(ws + off); off = align_up(off + (size_t)NN * H1 * 4, 256);
    int* rowptr = (int*)(ws + off); off = align_up(off + (size_t)(NN + 1) * 4, 256);
    int* deg    = (int*)(ws + off); off = align_up(off + (size_t)NN * 4, 256);
    int* fillc  = (int*)(ws + off); off = align_up(off + (size_t)NN * 4, 256);
    int* bsums  = (int*)(ws + off); off = align_up(off + 256 * 4, 256);
    int* csr_src = (int*)(ws + off); off = align_up(off + (size_t)EE * 4, 256);
    float* z2 = z1;  // z1 dead after layer-1 aggregation

    const int nScanBlocks = (NN + 255) / 256;   // 196
    const int nEdgeBlocks = (EE + 255) / 256;   // 3125

    // CSR build (by dst)
    hipMemsetAsync(deg, 0, (size_t)NN * 4, stream);
    hipMemsetAsync(fillc, 0, (size_t)NN * 4, stream);
    hist_kernel<<<nEdgeBlocks, 256, 0, stream>>>(dst, deg, EE);
    scan_block<<<nScanBlocks, 256, 0, stream>>>(deg, rowptr, bsums, NN);
    scan_bsums<<<1, 256, 0, stream>>>(bsums, nScanBlocks);
    add_offsets<<<nScanBlocks, 256, 0, stream>>>(rowptr, bsums, NN, EE);
    fill_csr<<<nEdgeBlocks, 256, 0, stream>>>(src, dst, rowptr, fillc, csr_src, EE);

    // ---- layer 1 ----
    {
        dim3 grid((FIN * 1 + 63) / 64, (NN + 63) / 64);  // Ncol = H1*HID = 256
        gemm_f32<<<dim3(4, (NN + 63) / 64), 256, 0, stream>>>(x, W1, z1, NN, H1 * HID, FIN);
    }
    node_scores<<<(NN * 64 + 255) / 256, 256, 0, stream>>>(z1, al1, ar1, el, er, NN, H1);
    gat_aggregate<<<(NN * H1 * 64 + 255) / 256, 256, 0, stream>>>(
        z1, el, er, rowptr, csr_src, b1, h1, NN, H1, 1);

    // ---- layer 2 ----
    gemm_f32<<<dim3(1, (NN + 63) / 64), 256, 0, stream>>>(h1, W2, z2, NN, H2 * OUTD, H1 * HID);
    node_scores<<<(NN * 64 + 255) / 256, 256, 0, stream>>>(z2, al2, ar2, el, er, NN, H2);
    gat_aggregate<<<(NN * H2 * 64 + 255) / 256, 256, 0, stream>>>(
        z2, el, er, rowptr, csr_src, b2, out, NN, H2, 0);
}

// Round 3
// 437.251 us; speedup vs baseline: 1.5964x; 1.5964x over previous
//
#include <hip/hip_runtime.h>
#include <hip/hip_bf16.h>
#include <math.h>

#define NN 50000
#define EE 800000
#define FIN 256
#define HID 64
#define OUTD 64
#define H1 4
#define H2 1

// ---------------- CSR build ----------------

__global__ void hist_kernel(const int* __restrict__ dst, int* __restrict__ deg, int nE) {
    int e = blockIdx.x * 256 + threadIdx.x;
    if (e < nE) atomicAdd(&deg[dst[e]], 1);
}

__global__ void scan_block(const int* __restrict__ in, int* __restrict__ out,
                           int* __restrict__ bsums, int n) {
    __shared__ int sh[256];
    int i = blockIdx.x * 256 + threadIdx.x;
    int v = (i < n) ? in[i] : 0;
    sh[threadIdx.x] = v;
    __syncthreads();
    for (int off = 1; off < 256; off <<= 1) {
        int t = 0;
        if (threadIdx.x >= off) t = sh[threadIdx.x - off];
        __syncthreads();
        if (threadIdx.x >= off) sh[threadIdx.x] += t;
        __syncthreads();
    }
    if (i < n) out[i] = sh[threadIdx.x] - v;          // exclusive
    if (threadIdx.x == 255) bsums[blockIdx.x] = sh[255];
}

__global__ void scan_bsums(int* __restrict__ bsums, int nb) {
    __shared__ int sh[256];
    int v = (threadIdx.x < nb) ? bsums[threadIdx.x] : 0;
    sh[threadIdx.x] = v;
    __syncthreads();
    for (int off = 1; off < 256; off <<= 1) {
        int t = 0;
        if (threadIdx.x >= off) t = sh[threadIdx.x - off];
        __syncthreads();
        if (threadIdx.x >= off) sh[threadIdx.x] += t;
        __syncthreads();
    }
    if (threadIdx.x < nb) bsums[threadIdx.x] = sh[threadIdx.x] - v;  // exclusive
}

__global__ void add_offsets(int* __restrict__ out, const int* __restrict__ bsums,
                            int n, int Etot) {
    int i = blockIdx.x * 256 + threadIdx.x;
    if (i < n) out[i] += bsums[blockIdx.x];
    if (i == 0) out[n] = Etot;
}

__global__ void fill_csr(const int* __restrict__ src, const int* __restrict__ dst,
                         const int* __restrict__ rowptr, int* __restrict__ fillc,
                         int* __restrict__ csr_src, int nE) {
    int e = blockIdx.x * 256 + threadIdx.x;
    if (e < nE) {
        int d = dst[e];
        int pos = rowptr[d] + atomicAdd(&fillc[d], 1);
        csr_src[pos] = src[e];
    }
}

// ---------------- f32 tiled GEMM: C[M,Ncol] = A[M,K] @ B[K,Ncol] ----------------
// BM=64, BN=64, BK=16, 256 threads, 4x4 micro-tile, float4 LDS reads.

__global__ __launch_bounds__(256) void gemm_f32(
    const float* __restrict__ A, const float* __restrict__ B, float* __restrict__ C,
    int M, int Ncol, int K)
{
    __shared__ __align__(16) float As[16][68];   // row stride 272B (16B aligned)
    __shared__ __align__(16) float Bs[16][64];
    int bm = blockIdx.y * 64, bn = blockIdx.x * 64;
    int tid = threadIdx.x;
    int tr = tid >> 4, tc = tid & 15;
    float acc[4][4] = {};

    for (int k0 = 0; k0 < K; k0 += 16) {
        int ar = tid >> 2;
        int ac = (tid & 3) * 4;
        int arow = bm + ar;
        float4 av = make_float4(0.f, 0.f, 0.f, 0.f);
        if (arow < M) av = *(const float4*)(A + (size_t)arow * K + k0 + ac);
        As[ac + 0][ar] = av.x; As[ac + 1][ar] = av.y;
        As[ac + 2][ar] = av.z; As[ac + 3][ar] = av.w;
        int br = tid >> 4;
        int bc = (tid & 15) * 4;
        float4 bv = make_float4(0.f, 0.f, 0.f, 0.f);
        if (bn + bc < Ncol) bv = *(const float4*)(B + (size_t)(k0 + br) * Ncol + bn + bc);
        *(float4*)&Bs[br][bc] = bv;
        __syncthreads();
#pragma unroll
        for (int kk = 0; kk < 16; ++kk) {
            float4 a4 = *(const float4*)&As[kk][tr * 4];
            float4 b4 = *(const float4*)&Bs[kk][tc * 4];
            acc[0][0] += a4.x * b4.x; acc[0][1] += a4.x * b4.y; acc[0][2] += a4.x * b4.z; acc[0][3] += a4.x * b4.w;
            acc[1][0] += a4.y * b4.x; acc[1][1] += a4.y * b4.y; acc[1][2] += a4.y * b4.z; acc[1][3] += a4.y * b4.w;
            acc[2][0] += a4.z * b4.x; acc[2][1] += a4.z * b4.y; acc[2][2] += a4.z * b4.z; acc[2][3] += a4.z * b4.w;
            acc[3][0] += a4.w * b4.x; acc[3][1] += a4.w * b4.y; acc[3][2] += a4.w * b4.z; acc[3][3] += a4.w * b4.w;
        }
        __syncthreads();
    }
#pragma unroll
    for (int i = 0; i < 4; ++i) {
        int row = bm + tr * 4 + i;
        if (row < M) {
            int col = bn + tc * 4;
            if (col < Ncol) {
                float4 v = make_float4(acc[i][0], acc[i][1], acc[i][2], acc[i][3]);
                *(float4*)(C + (size_t)row * Ncol + col) = v;
            }
        }
    }
}

// ---------------- per-node attention scores: el/er [N,H] ----------------

__global__ void node_scores(const float* __restrict__ z, const float* __restrict__ al,
                            const float* __restrict__ ar, float* __restrict__ el,
                            float* __restrict__ er, int Nn, int H) {
    int wave = (blockIdx.x * blockDim.x + threadIdx.x) >> 6;
    int lane = threadIdx.x & 63;
    if (wave >= Nn) return;
    for (int h = 0; h < H; ++h) {
        float zv = z[(size_t)wave * H * 64 + h * 64 + lane];
        float sl = zv * al[h * 64 + lane];
        float sr = zv * ar[h * 64 + lane];
#pragma unroll
        for (int off = 32; off; off >>= 1) {
            sl += __shfl_xor(sl, off);
            sr += __shfl_xor(sr, off);
        }
        if (lane == 0) {
            el[wave * H + h] = sl;
            er[wave * H + h] = sr;
        }
    }
}

// ---------------- edge-softmax + aggregation (register edge cache, 4-edge groups) ----
// one wave per (node, head); lanes cache up to 64 edges; online softmax over chunks;
// weighted gather: 4 groups of 16 lanes, each group reads one 256B z-row (float4/lane).
// NOTE: gather loop trip count is wave-uniform; __shfl runs with all 64 lanes active
// (shfl from an EXEC-disabled lane is undefined on CDNA — that was round-1's bug).

__global__ void gat_aggregate(const float* __restrict__ z, const float* __restrict__ el,
                              const float* __restrict__ er, const int* __restrict__ rowptr,
                              const int* __restrict__ csr_src, const float* __restrict__ bias,
                              float* __restrict__ out, int Nn, int H, int do_elu)
{
    const int HZ = H * 64;
    int gw = (blockIdx.x * blockDim.x + threadIdx.x) >> 6;
    int lane = threadIdx.x & 63;
    int n = gw / H;
    int h = gw - n * H;
    if (n >= Nn) return;
    int start = rowptr[n], end = rowptr[n + 1];
    int deg = end - start;
    float ern = er[n * H + h];

    int group = lane >> 4;      // 0..3
    int gl = lane & 15;         // 0..15

    float4 acc = make_float4(0.f, 0.f, 0.f, 0.f);
    float m = -INFINITY;
    float ssum = 0.f;

    for (int c0 = 0; c0 < deg; c0 += 64) {
        int nc = min(64, deg - c0);
        // lane e: load edge, compute leaky-relu score
        int s_l = 0;
        float e_l = -INFINITY;
        if (lane < nc) {
            s_l = csr_src[start + c0 + lane];
            float e = el[s_l * H + h] + ern;
            e_l = e > 0.f ? e : 0.2f * e;
        }
        // chunk max (wave reduce)
        float cm = e_l;
#pragma unroll
        for (int off = 32; off; off >>= 1) cm = fmaxf(cm, __shfl_xor(cm, off));
        float newm = fmaxf(m, cm);               // finite (nc>=1)
        float scale = __expf(m - newm);          // 0 on first chunk (m=-inf)
        ssum *= scale;
        acc.x *= scale; acc.y *= scale; acc.z *= scale; acc.w *= scale;
        m = newm;
        float p_l = (lane < nc) ? __expf(e_l - m) : 0.f;
        float cs = p_l;
#pragma unroll
        for (int off = 32; off; off >>= 1) cs += __shfl_xor(cs, off);
        ssum += cs;
        // weighted gather: group g handles edges t = g + 4*i; uniform trip count,
        // shfl outside the predicate so all 64 lanes are active for it.
        int nIter = (nc + 3) >> 2;
        for (int i = 0; i < nIter; ++i) {
            int t = group + 4 * i;               // <= 63 always
            float w = __shfl(p_l, t);
            int s = __shfl(s_l, t);
            if (t < nc) {
                float4 v = *(const float4*)(z + (size_t)s * HZ + h * 64 + gl * 4);
                acc.x = fmaf(w, v.x, acc.x);
                acc.y = fmaf(w, v.y, acc.y);
                acc.z = fmaf(w, v.z, acc.z);
                acc.w = fmaf(w, v.w, acc.w);
            }
        }
    }
    // combine the 4 groups (butterfly over lane bits 4,5)
#pragma unroll
    for (int off = 16; off <= 32; off <<= 1) {
        acc.x += __shfl_xor(acc.x, off);
        acc.y += __shfl_xor(acc.y, off);
        acc.z += __shfl_xor(acc.z, off);
        acc.w += __shfl_xor(acc.w, off);
    }
    float inv = ssum > 0.f ? 1.f / ssum : 0.f;
    if (lane < 16) {
        float4 o;
        o.x = acc.x * inv + bias[h * 64 + gl * 4 + 0];
        o.y = acc.y * inv + bias[h * 64 + gl * 4 + 1];
        o.z = acc.z * inv + bias[h * 64 + gl * 4 + 2];
        o.w = acc.w * inv + bias[h * 64 + gl * 4 + 3];
        if (do_elu) {
            o.x = o.x > 0.f ? o.x : expm1f(o.x);
            o.y = o.y > 0.f ? o.y : expm1f(o.y);
            o.z = o.z > 0.f ? o.z : expm1f(o.z);
            o.w = o.w > 0.f ? o.w : expm1f(o.w);
        }
        *(float4*)(out + (size_t)n * HZ + h * 64 + gl * 4) = o;
    }
}

// ---------------- launch ----------------

static inline size_t align_up(size_t x, size_t a) { return (x + a - 1) & ~(a - 1); }

extern "C" void kernel_launch(void* const* d_in, const int* in_sizes, int n_in,
                              void* d_out, int out_size, void* d_ws, size_t ws_size,
                              hipStream_t stream) {
    const float* x   = (const float*)d_in[0];
    const float* W1  = (const float*)d_in[1];
    const float* al1 = (const float*)d_in[2];
    const float* ar1 = (const float*)d_in[3];
    const float* b1  = (const float*)d_in[4];
    const float* W2  = (const float*)d_in[5];
    const float* al2 = (const float*)d_in[6];
    const float* ar2 = (const float*)d_in[7];
    const float* b2  = (const float*)d_in[8];
    const int*   src = (const int*)d_in[9];
    const int*   dst = (const int*)d_in[10];
    float* out = (float*)d_out;

    char* ws = (char*)d_ws;
    size_t off = 0;
    float* z1 = (float*)(ws + off); off = align_up(off + (size_t)NN * FIN * 4, 256);   // reused as z2
    float* h1 = (float*)(ws + off); off = align_up(off + (size_t)NN * FIN * 4, 256);
    float* el = (float*)(ws + off); off = align_up(off + (size_t)NN * H1 * 4, 256);
    float* er = (float*)(ws + off); off = align_up(off + (size_t)NN * H1 * 4, 256);
    int* rowptr = (int*)(ws + off); off = align_up(off + (size_t)(NN + 1) * 4, 256);
    int* deg    = (int*)(ws + off); off = align_up(off + (size_t)NN * 4, 256);
    int* fillc  = (int*)(ws + off); off = align_up(off + (size_t)NN * 4, 256);
    int* bsums  = (int*)(ws + off); off = align_up(off + 256 * 4, 256);
    int* csr_src = (int*)(ws + off); off = align_up(off + (size_t)EE * 4, 256);
    float* z2 = z1;

    const int nScanBlocks = (NN + 255) / 256;
    const int nEdgeBlocks = (EE + 255) / 256;

    hipMemsetAsync(deg, 0, (size_t)NN * 4, stream);
    hipMemsetAsync(fillc, 0, (size_t)NN * 4, stream);
    hist_kernel<<<nEdgeBlocks, 256, 0, stream>>>(dst, deg, EE);
    scan_block<<<nScanBlocks, 256, 0, stream>>>(deg, rowptr, bsums, NN);
    scan_bsums<<<1, 256, 0, stream>>>(bsums, nScanBlocks);
    add_offsets<<<nScanBlocks, 256, 0, stream>>>(rowptr, bsums, NN, EE);
    fill_csr<<<nEdgeBlocks, 256, 0, stream>>>(src, dst, rowptr, fillc, csr_src, EE);

    // ---- layer 1 ----
    gemm_f32<<<dim3(4, (NN + 63) / 64), 256, 0, stream>>>(x, W1, z1, NN, H1 * HID, FIN);
    node_scores<<<(NN * 64 + 255) / 256, 256, 0, stream>>>(z1, al1, ar1, el, er, NN, H1);
    gat_aggregate<<<(NN * H1 * 64 + 255) / 256, 256, 0, stream>>>(
        z1, el, er, rowptr, csr_src, b1, h1, NN, H1, 1);

    // ---- layer 2 ----
    gemm_f32<<<dim3(1, (NN + 63) / 64), 256, 0, stream>>>(h1, W2, z2, NN, H2 * OUTD, H1 * HID);
    node_scores<<<(NN * 64 + 255) / 256, 256, 0, stream>>>(z2, al2, ar2, el, er, NN, H2);
    gat_aggregate<<<(NN * H2 * 64 + 255) / 256, 256, 0, stream>>>(
        z2, el, er, rowptr, csr_src, b2, out, NN, H2, 0);
}

// Round 4
// 376.363 us; speedup vs baseline: 1.8547x; 1.1618x over previous
//
#include <hip/hip_runtime.h>
#include <hip/hip_bf16.h>
#include <math.h>

#define NN 50000
#define EE 800000
#define FIN 256
#define HID 64
#define OUTD 64
#define H1 4
#define H2 1

// ---------------- helpers ----------------

__device__ __forceinline__ unsigned short f2bf(float f) {   // round-to-nearest-even
    unsigned u = __float_as_uint(f);
    unsigned r = (u + 0x7FFFu + ((u >> 16) & 1u)) >> 16;
    return (unsigned short)r;
}
__device__ __forceinline__ float bf2f(unsigned short u) {
    return __uint_as_float(((unsigned)u) << 16);
}

// ---------------- CSR build ----------------

__global__ void hist_kernel(const int* __restrict__ dst, int* __restrict__ deg, int nE) {
    int e = blockIdx.x * 256 + threadIdx.x;
    if (e < nE) atomicAdd(&deg[dst[e]], 1);
}

__global__ void scan_block(const int* __restrict__ in, int* __restrict__ out,
                           int* __restrict__ bsums, int n) {
    __shared__ int sh[256];
    int i = blockIdx.x * 256 + threadIdx.x;
    int v = (i < n) ? in[i] : 0;
    sh[threadIdx.x] = v;
    __syncthreads();
    for (int off = 1; off < 256; off <<= 1) {
        int t = 0;
        if (threadIdx.x >= off) t = sh[threadIdx.x - off];
        __syncthreads();
        if (threadIdx.x >= off) sh[threadIdx.x] += t;
        __syncthreads();
    }
    if (i < n) out[i] = sh[threadIdx.x] - v;          // exclusive
    if (threadIdx.x == 255) bsums[blockIdx.x] = sh[255];
}

__global__ void scan_bsums(int* __restrict__ bsums, int nb) {
    __shared__ int sh[256];
    int v = (threadIdx.x < nb) ? bsums[threadIdx.x] : 0;
    sh[threadIdx.x] = v;
    __syncthreads();
    for (int off = 1; off < 256; off <<= 1) {
        int t = 0;
        if (threadIdx.x >= off) t = sh[threadIdx.x - off];
        __syncthreads();
        if (threadIdx.x >= off) sh[threadIdx.x] += t;
        __syncthreads();
    }
    if (threadIdx.x < nb) bsums[threadIdx.x] = sh[threadIdx.x] - v;  // exclusive
}

__global__ void add_offsets(int* __restrict__ out, const int* __restrict__ bsums,
                            int n, int Etot) {
    int i = blockIdx.x * 256 + threadIdx.x;
    if (i < n) out[i] += bsums[blockIdx.x];
    if (i == 0) out[n] = Etot;
}

__global__ void fill_csr(const int* __restrict__ src, const int* __restrict__ dst,
                         const int* __restrict__ rowptr, int* __restrict__ fillc,
                         int* __restrict__ csr_src, int nE) {
    int e = blockIdx.x * 256 + threadIdx.x;
    if (e < nE) {
        int d = dst[e];
        int pos = rowptr[d] + atomicAdd(&fillc[d], 1);
        csr_src[pos] = src[e];
    }
}

// ---------------- f32 tiled GEMM ----------------

__global__ __launch_bounds__(256) void gemm_f32(
    const float* __restrict__ A, const float* __restrict__ B, float* __restrict__ C,
    int M, int Ncol, int K)
{
    __shared__ __align__(16) float As[16][68];
    __shared__ __align__(16) float Bs[16][64];
    int bm = blockIdx.y * 64, bn = blockIdx.x * 64;
    int tid = threadIdx.x;
    int tr = tid >> 4, tc = tid & 15;
    float acc[4][4] = {};

    for (int k0 = 0; k0 < K; k0 += 16) {
        int ar = tid >> 2;
        int ac = (tid & 3) * 4;
        int arow = bm + ar;
        float4 av = make_float4(0.f, 0.f, 0.f, 0.f);
        if (arow < M) av = *(const float4*)(A + (size_t)arow * K + k0 + ac);
        As[ac + 0][ar] = av.x; As[ac + 1][ar] = av.y;
        As[ac + 2][ar] = av.z; As[ac + 3][ar] = av.w;
        int br = tid >> 4;
        int bc = (tid & 15) * 4;
        float4 bv = make_float4(0.f, 0.f, 0.f, 0.f);
        if (bn + bc < Ncol) bv = *(const float4*)(B + (size_t)(k0 + br) * Ncol + bn + bc);
        *(float4*)&Bs[br][bc] = bv;
        __syncthreads();
#pragma unroll
        for (int kk = 0; kk < 16; ++kk) {
            float4 a4 = *(const float4*)&As[kk][tr * 4];
            float4 b4 = *(const float4*)&Bs[kk][tc * 4];
            acc[0][0] += a4.x * b4.x; acc[0][1] += a4.x * b4.y; acc[0][2] += a4.x * b4.z; acc[0][3] += a4.x * b4.w;
            acc[1][0] += a4.y * b4.x; acc[1][1] += a4.y * b4.y; acc[1][2] += a4.y * b4.z; acc[1][3] += a4.y * b4.w;
            acc[2][0] += a4.z * b4.x; acc[2][1] += a4.z * b4.y; acc[2][2] += a4.z * b4.z; acc[2][3] += a4.z * b4.w;
            acc[3][0] += a4.w * b4.x; acc[3][1] += a4.w * b4.y; acc[3][2] += a4.w * b4.z; acc[3][3] += a4.w * b4.w;
        }
        __syncthreads();
    }
#pragma unroll
    for (int i = 0; i < 4; ++i) {
        int row = bm + tr * 4 + i;
        if (row < M) {
            int col = bn + tc * 4;
            if (col < Ncol) {
                float4 v = make_float4(acc[i][0], acc[i][1], acc[i][2], acc[i][3]);
                *(float4*)(C + (size_t)row * Ncol + col) = v;
            }
        }
    }
}

// ---------------- per-node attention scores + bf16 copy of z ----------------

__global__ void node_scores(const float* __restrict__ z, const float* __restrict__ al,
                            const float* __restrict__ ar, float* __restrict__ el,
                            float* __restrict__ er, unsigned short* __restrict__ zb,
                            int Nn, int H) {
    int wave = (blockIdx.x * blockDim.x + threadIdx.x) >> 6;
    int lane = threadIdx.x & 63;
    if (wave >= Nn) return;
    for (int h = 0; h < H; ++h) {
        size_t idx = (size_t)wave * H * 64 + h * 64 + lane;
        float zv = z[idx];
        zb[idx] = f2bf(zv);
        float sl = zv * al[h * 64 + lane];
        float sr = zv * ar[h * 64 + lane];
#pragma unroll
        for (int off = 32; off; off >>= 1) {
            sl += __shfl_xor(sl, off);
            sr += __shfl_xor(sr, off);
        }
        if (lane == 0) {
            el[wave * H + h] = sl;
            er[wave * H + h] = sr;
        }
    }
}

// ---------------- layer-1 aggregate: one wave per node, 4 heads merged ----------------
// lane owns channels [lane*4, lane*4+4) of the 256-wide (head-major) row;
// head of a lane = lane>>4. Single node-wide softmax max (cancels in alpha).
// Per-edge weights broadcast via small LDS table (16-lane broadcast, conflict-free).

__global__ __launch_bounds__(256) void gat_aggregate_h4(
    const unsigned short* __restrict__ zb,   // [N,256] bf16
    const float* __restrict__ el,            // [N,4]
    const float* __restrict__ er,            // [N,4]
    const int* __restrict__ rowptr, const int* __restrict__ csr_src,
    const float* __restrict__ bias,          // [256]
    float* __restrict__ out,                 // [N,256] f32 (ELU applied)
    int Nn)
{
    __shared__ float p_lds[4][64][4];
    __shared__ int   s_lds[4][64];
    int wid = threadIdx.x >> 6;
    int lane = threadIdx.x & 63;
    int n = blockIdx.x * 4 + wid;
    if (n >= Nn) return;
    int start = rowptr[n], end = rowptr[n + 1];
    int deg = end - start;
    float4 er4 = *(const float4*)(er + (size_t)n * 4);
    int hsel = lane >> 4;

    float4 acc = make_float4(0.f, 0.f, 0.f, 0.f);
    float4 ssum = make_float4(0.f, 0.f, 0.f, 0.f);
    float m = -INFINITY;

    for (int c0 = 0; c0 < deg; c0 += 64) {
        int nc = min(64, deg - c0);
        int s_l = 0;
        float4 e4 = make_float4(-INFINITY, -INFINITY, -INFINITY, -INFINITY);
        float emax_l = -INFINITY;
        if (lane < nc) {
            s_l = csr_src[start + c0 + lane];
            float4 el4 = *(const float4*)(el + (size_t)s_l * 4);
            e4.x = el4.x + er4.x; e4.x = e4.x > 0.f ? e4.x : 0.2f * e4.x;
            e4.y = el4.y + er4.y; e4.y = e4.y > 0.f ? e4.y : 0.2f * e4.y;
            e4.z = el4.z + er4.z; e4.z = e4.z > 0.f ? e4.z : 0.2f * e4.z;
            e4.w = el4.w + er4.w; e4.w = e4.w > 0.f ? e4.w : 0.2f * e4.w;
            emax_l = fmaxf(fmaxf(e4.x, e4.y), fmaxf(e4.z, e4.w));
        }
        float cm = emax_l;
#pragma unroll
        for (int off = 32; off; off >>= 1) cm = fmaxf(cm, __shfl_xor(cm, off));
        float newm = fmaxf(m, cm);              // finite (nc >= 1)
        float scale = __expf(m - newm);         // 0 on first chunk
        ssum.x *= scale; ssum.y *= scale; ssum.z *= scale; ssum.w *= scale;
        acc.x *= scale;  acc.y *= scale;  acc.z *= scale;  acc.w *= scale;
        m = newm;
        float4 p4 = make_float4(0.f, 0.f, 0.f, 0.f);
        if (lane < nc) {
            p4.x = __expf(e4.x - m);
            p4.y = __expf(e4.y - m);
            p4.z = __expf(e4.z - m);
            p4.w = __expf(e4.w - m);
        }
        float4 cs = p4;
#pragma unroll
        for (int off = 32; off; off >>= 1) {
            cs.x += __shfl_xor(cs.x, off);
            cs.y += __shfl_xor(cs.y, off);
            cs.z += __shfl_xor(cs.z, off);
            cs.w += __shfl_xor(cs.w, off);
        }
        ssum.x += cs.x; ssum.y += cs.y; ssum.z += cs.z; ssum.w += cs.w;
        // stash weights + srcs for broadcast
        *(float4*)&p_lds[wid][lane][0] = p4;
        s_lds[wid][lane] = s_l;
        // gather: edge t -> whole 512B bf16 row by 64 lanes (8B each)
#pragma unroll 2
        for (int t = 0; t < nc; ++t) {
            float w = p_lds[wid][t][hsel];
            int s = s_lds[wid][t];
            ushort4 u = *(const ushort4*)(zb + (size_t)s * 256 + lane * 4);
            acc.x = fmaf(w, bf2f(u.x), acc.x);
            acc.y = fmaf(w, bf2f(u.y), acc.y);
            acc.z = fmaf(w, bf2f(u.z), acc.z);
            acc.w = fmaf(w, bf2f(u.w), acc.w);
        }
    }
    float s_h = hsel == 0 ? ssum.x : hsel == 1 ? ssum.y : hsel == 2 ? ssum.z : ssum.w;
    float inv = s_h > 0.f ? 1.f / s_h : 0.f;
    float4 b4 = *(const float4*)(bias + lane * 4);
    float4 o;
    o.x = acc.x * inv + b4.x; o.x = o.x > 0.f ? o.x : expm1f(o.x);
    o.y = acc.y * inv + b4.y; o.y = o.y > 0.f ? o.y : expm1f(o.y);
    o.z = acc.z * inv + b4.z; o.z = o.z > 0.f ? o.z : expm1f(o.z);
    o.w = acc.w * inv + b4.w; o.w = o.w > 0.f ? o.w : expm1f(o.w);
    *(float4*)(out + (size_t)n * 256 + lane * 4) = o;
}

// ---------------- layer-2 aggregate (H=1), bf16 gather, 4-edge groups ----------------

__global__ void gat_aggregate_bf(const unsigned short* __restrict__ zb,  // [N,64] bf16
                                 const float* __restrict__ el, const float* __restrict__ er,
                                 const int* __restrict__ rowptr, const int* __restrict__ csr_src,
                                 const float* __restrict__ bias,
                                 float* __restrict__ out, int Nn)
{
    int gw = (blockIdx.x * blockDim.x + threadIdx.x) >> 6;
    int lane = threadIdx.x & 63;
    int n = gw;
    if (n >= Nn) return;
    int start = rowptr[n], end = rowptr[n + 1];
    int deg = end - start;
    float ern = er[n];

    int group = lane >> 4;
    int gl = lane & 15;

    float4 acc = make_float4(0.f, 0.f, 0.f, 0.f);
    float m = -INFINITY;
    float ssum = 0.f;

    for (int c0 = 0; c0 < deg; c0 += 64) {
        int nc = min(64, deg - c0);
        int s_l = 0;
        float e_l = -INFINITY;
        if (lane < nc) {
            s_l = csr_src[start + c0 + lane];
            float e = el[s_l] + ern;
            e_l = e > 0.f ? e : 0.2f * e;
        }
        float cm = e_l;
#pragma unroll
        for (int off = 32; off; off >>= 1) cm = fmaxf(cm, __shfl_xor(cm, off));
        float newm = fmaxf(m, cm);
        float scale = __expf(m - newm);
        ssum *= scale;
        acc.x *= scale; acc.y *= scale; acc.z *= scale; acc.w *= scale;
        m = newm;
        float p_l = (lane < nc) ? __expf(e_l - m) : 0.f;
        float cs = p_l;
#pragma unroll
        for (int off = 32; off; off >>= 1) cs += __shfl_xor(cs, off);
        ssum += cs;
        int nIter = (nc + 3) >> 2;
        for (int i = 0; i < nIter; ++i) {
            int t = group + 4 * i;
            float w = __shfl(p_l, t);
            int s = __shfl(s_l, t);
            if (t < nc) {
                ushort4 u = *(const ushort4*)(zb + (size_t)s * 64 + gl * 4);
                acc.x = fmaf(w, bf2f(u.x), acc.x);
                acc.y = fmaf(w, bf2f(u.y), acc.y);
                acc.z = fmaf(w, bf2f(u.z), acc.z);
                acc.w = fmaf(w, bf2f(u.w), acc.w);
            }
        }
    }
#pragma unroll
    for (int off = 16; off <= 32; off <<= 1) {
        acc.x += __shfl_xor(acc.x, off);
        acc.y += __shfl_xor(acc.y, off);
        acc.z += __shfl_xor(acc.z, off);
        acc.w += __shfl_xor(acc.w, off);
    }
    float inv = ssum > 0.f ? 1.f / ssum : 0.f;
    if (lane < 16) {
        float4 o;
        o.x = acc.x * inv + bias[gl * 4 + 0];
        o.y = acc.y * inv + bias[gl * 4 + 1];
        o.z = acc.z * inv + bias[gl * 4 + 2];
        o.w = acc.w * inv + bias[gl * 4 + 3];
        *(float4*)(out + (size_t)n * 64 + gl * 4) = o;
    }
}

// ---------------- launch ----------------

static inline size_t align_up(size_t x, size_t a) { return (x + a - 1) & ~(a - 1); }

extern "C" void kernel_launch(void* const* d_in, const int* in_sizes, int n_in,
                              void* d_out, int out_size, void* d_ws, size_t ws_size,
                              hipStream_t stream) {
    const float* x   = (const float*)d_in[0];
    const float* W1  = (const float*)d_in[1];
    const float* al1 = (const float*)d_in[2];
    const float* ar1 = (const float*)d_in[3];
    const float* b1  = (const float*)d_in[4];
    const float* W2  = (const float*)d_in[5];
    const float* al2 = (const float*)d_in[6];
    const float* ar2 = (const float*)d_in[7];
    const float* b2  = (const float*)d_in[8];
    const int*   src = (const int*)d_in[9];
    const int*   dst = (const int*)d_in[10];
    float* out = (float*)d_out;

    char* ws = (char*)d_ws;
    size_t off = 0;
    float* z1 = (float*)(ws + off); off = align_up(off + (size_t)NN * FIN * 4, 256);   // reused as z2
    float* h1 = (float*)(ws + off); off = align_up(off + (size_t)NN * FIN * 4, 256);
    unsigned short* zb = (unsigned short*)(ws + off); off = align_up(off + (size_t)NN * FIN * 2, 256); // bf16 z copy (reused L2)
    float* el = (float*)(ws + off); off = align_up(off + (size_t)NN * H1 * 4, 256);
    float* er = (float*)(ws + off); off = align_up(off + (size_t)NN * H1 * 4, 256);
    int* rowptr = (int*)(ws + off); off = align_up(off + (size_t)(NN + 1) * 4, 256);
    int* deg    = (int*)(ws + off); off = align_up(off + (size_t)NN * 4, 256);
    int* fillc  = (int*)(ws + off); off = align_up(off + (size_t)NN * 4, 256);
    int* bsums  = (int*)(ws + off); off = align_up(off + 256 * 4, 256);
    int* csr_src = (int*)(ws + off); off = align_up(off + (size_t)EE * 4, 256);
    float* z2 = z1;

    const int nScanBlocks = (NN + 255) / 256;
    const int nEdgeBlocks = (EE + 255) / 256;

    hipMemsetAsync(deg, 0, (size_t)NN * 4, stream);
    hipMemsetAsync(fillc, 0, (size_t)NN * 4, stream);
    hist_kernel<<<nEdgeBlocks, 256, 0, stream>>>(dst, deg, EE);
    scan_block<<<nScanBlocks, 256, 0, stream>>>(deg, rowptr, bsums, NN);
    scan_bsums<<<1, 256, 0, stream>>>(bsums, nScanBlocks);
    add_offsets<<<nScanBlocks, 256, 0, stream>>>(rowptr, bsums, NN, EE);
    fill_csr<<<nEdgeBlocks, 256, 0, stream>>>(src, dst, rowptr, fillc, csr_src, EE);

    // ---- layer 1 ----
    gemm_f32<<<dim3(4, (NN + 63) / 64), 256, 0, stream>>>(x, W1, z1, NN, H1 * HID, FIN);
    node_scores<<<(NN * 64 + 255) / 256, 256, 0, stream>>>(z1, al1, ar1, el, er, zb, NN, H1);
    gat_aggregate_h4<<<(NN + 3) / 4, 256, 0, stream>>>(
        zb, el, er, rowptr, csr_src, b1, h1, NN);

    // ---- layer 2 ----
    gemm_f32<<<dim3(1, (NN + 63) / 64), 256, 0, stream>>>(h1, W2, z2, NN, H2 * OUTD, H1 * HID);
    node_scores<<<(NN * 64 + 255) / 256, 256, 0, stream>>>(z2, al2, ar2, el, er, zb, NN, H2);
    gat_aggregate_bf<<<(NN * 64 + 255) / 256, 256, 0, stream>>>(
        zb, el, er, rowptr, csr_src, b2, out, NN);
}

// Round 5
// 281.274 us; speedup vs baseline: 2.4817x; 1.3381x over previous
//
#include <hip/hip_runtime.h>
#include <hip/hip_bf16.h>
#include <math.h>

#define NN 50000
#define EE 800000
#define FIN 256
#define HID 64
#define OUTD 64
#define H1 4
#define H2 1

typedef __attribute__((ext_vector_type(8))) short short8;
typedef __attribute__((ext_vector_type(4))) short short4v;
typedef __attribute__((ext_vector_type(4))) float f32x4;

// ---------------- helpers ----------------

__device__ __forceinline__ unsigned short f2bf(float f) {   // round-to-nearest-even
    unsigned u = __float_as_uint(f);
    unsigned r = (u + 0x7FFFu + ((u >> 16) & 1u)) >> 16;
    return (unsigned short)r;
}
__device__ __forceinline__ float bf2f(unsigned short u) {
    return __uint_as_float(((unsigned)u) << 16);
}

// ---------------- CSR build ----------------

__global__ void hist_kernel(const int* __restrict__ dst, int* __restrict__ deg, int nE) {
    int e = blockIdx.x * 256 + threadIdx.x;
    if (e < nE) atomicAdd(&deg[dst[e]], 1);
}

__global__ void scan_block(const int* __restrict__ in, int* __restrict__ out,
                           int* __restrict__ bsums, int n) {
    __shared__ int sh[256];
    int i = blockIdx.x * 256 + threadIdx.x;
    int v = (i < n) ? in[i] : 0;
    sh[threadIdx.x] = v;
    __syncthreads();
    for (int off = 1; off < 256; off <<= 1) {
        int t = 0;
        if (threadIdx.x >= off) t = sh[threadIdx.x - off];
        __syncthreads();
        if (threadIdx.x >= off) sh[threadIdx.x] += t;
        __syncthreads();
    }
    if (i < n) out[i] = sh[threadIdx.x] - v;          // exclusive
    if (threadIdx.x == 255) bsums[blockIdx.x] = sh[255];
}

__global__ void scan_bsums(int* __restrict__ bsums, int nb) {
    __shared__ int sh[256];
    int v = (threadIdx.x < nb) ? bsums[threadIdx.x] : 0;
    sh[threadIdx.x] = v;
    __syncthreads();
    for (int off = 1; off < 256; off <<= 1) {
        int t = 0;
        if (threadIdx.x >= off) t = sh[threadIdx.x - off];
        __syncthreads();
        if (threadIdx.x >= off) sh[threadIdx.x] += t;
        __syncthreads();
    }
    if (threadIdx.x < nb) bsums[threadIdx.x] = sh[threadIdx.x] - v;  // exclusive
}

__global__ void add_offsets(int* __restrict__ out, const int* __restrict__ bsums,
                            int n, int Etot) {
    int i = blockIdx.x * 256 + threadIdx.x;
    if (i < n) out[i] += bsums[blockIdx.x];
    if (i == 0) out[n] = Etot;
}

__global__ void fill_csr(const int* __restrict__ src, const int* __restrict__ dst,
                         const int* __restrict__ rowptr, int* __restrict__ fillc,
                         int* __restrict__ csr_src, int nE) {
    int e = blockIdx.x * 256 + threadIdx.x;
    if (e < nE) {
        int d = dst[e];
        int pos = rowptr[d] + atomicAdd(&fillc[d], 1);
        csr_src[pos] = src[e];
    }
}

// ---------------- weight prep: transpose + split f32 -> bf16 hi/lo ----------------
// W1 [256][256] -> W1t[n][k]; W2 [256][64] -> W2t[n][k]. grid 320 x 256 threads.

__global__ void wsplit(const float* __restrict__ W1, const float* __restrict__ W2,
                       short* __restrict__ W1th, short* __restrict__ W1tl,
                       short* __restrict__ W2th, short* __restrict__ W2tl) {
    int n = blockIdx.x;
    int k = threadIdx.x;
    if (n < 256) {
        float v = W1[(size_t)k * 256 + n];
        unsigned short hi = f2bf(v);
        unsigned short lo = f2bf(v - bf2f(hi));
        W1th[n * 256 + k] = (short)hi;
        W1tl[n * 256 + k] = (short)lo;
    } else {
        int n2 = n - 256;
        float v = W2[(size_t)k * 64 + n2];
        unsigned short hi = f2bf(v);
        unsigned short lo = f2bf(v - bf2f(hi));
        W2th[n2 * 256 + k] = (short)hi;
        W2tl[n2 * 256 + k] = (short)lo;
    }
}

// ---------------- MFMA GEMM (split-bf16, 3-pass) + fused scores epilogue ----------
// C[M,NT] = A[M,K] @ B[K,NT]; B pre-transposed/split as Bt[n][k] bf16 hi/lo.
// BM = 128 (WR*MF*16), BN = WC*64, BK = 32, 4 waves, wave tile = MF*16 x 64.
// Each wave's 64-col span is exactly one head: epilogue emits zb (bf16) and el/er.

template<int MF, int WR, int WC, int NT, int H>
__global__ __launch_bounds__(256) void gemm_bf16x2(
    const float* __restrict__ A, const short* __restrict__ Bth, const short* __restrict__ Btl,
    const float* __restrict__ al, const float* __restrict__ ar,
    unsigned short* __restrict__ zb, float* __restrict__ el, float* __restrict__ er,
    int M, int K)
{
    constexpr int BM = WR * MF * 16;   // 128
    constexpr int BN = WC * 64;
    __shared__ short Ah[128 * 40], Al[128 * 40];
    __shared__ short Bh[BN * 40], Bl[BN * 40];

    const int bm = blockIdx.x * BM;
    const int bn = blockIdx.y * BN;
    const int t = threadIdx.x;
    const int wid = t >> 6;
    const int lane = t & 63;
    const int lr = lane & 15;
    const int lg = lane >> 4;
    const int wr = wid / WC;
    const int wc = wid % WC;

    f32x4 acc[MF][4];
#pragma unroll
    for (int mf = 0; mf < MF; ++mf)
#pragma unroll
        for (int nf = 0; nf < 4; ++nf) acc[mf][nf] = (f32x4)(0.f);

    for (int k0 = 0; k0 < K; k0 += 32) {
        // ---- stage A: 128x32 f32 -> hi/lo bf16, rows padded to stride 40 ----
#pragma unroll
        for (int q = 0; q < 4; ++q) {
            int linear = q * 256 + t;       // 0..1023
            int row = linear >> 3;          // 0..127
            int kq = (linear & 7) * 4;      // 0..28
            int grow = bm + row;
            float4 av = make_float4(0.f, 0.f, 0.f, 0.f);
            if (grow < M) av = *(const float4*)(A + (size_t)grow * K + k0 + kq);
            short4v hi, lo;
            unsigned short h0 = f2bf(av.x); hi.x = (short)h0; lo.x = (short)f2bf(av.x - bf2f(h0));
            unsigned short h1v = f2bf(av.y); hi.y = (short)h1v; lo.y = (short)f2bf(av.y - bf2f(h1v));
            unsigned short h2v = f2bf(av.z); hi.z = (short)h2v; lo.z = (short)f2bf(av.z - bf2f(h2v));
            unsigned short h3v = f2bf(av.w); hi.w = (short)h3v; lo.w = (short)f2bf(av.w - bf2f(h3v));
            *(short4v*)&Ah[row * 40 + kq] = hi;
            *(short4v*)&Al[row * 40 + kq] = lo;
        }
        // ---- stage B: BN x 32 bf16 hi/lo from pre-split Bt[n][k] ----
#pragma unroll
        for (int q = 0; q < BN / 64; ++q) {
            int linear = q * 256 + t;       // n-chunks
            int n = linear >> 2;            // 0..BN-1
            int k8 = (linear & 3) * 8;
            short8 vh = *(const short8*)(Bth + (size_t)(bn + n) * K + k0 + k8);
            short8 vl = *(const short8*)(Btl + (size_t)(bn + n) * K + k0 + k8);
            *(short8*)&Bh[n * 40 + k8] = vh;
            *(short8*)&Bl[n * 40 + k8] = vl;
        }
        __syncthreads();

        short8 ah[MF], alo[MF], bh[4], blo[4];
#pragma unroll
        for (int mf = 0; mf < MF; ++mf) {
            int row = wr * MF * 16 + mf * 16 + lr;
            ah[mf]  = *(const short8*)&Ah[row * 40 + lg * 8];
            alo[mf] = *(const short8*)&Al[row * 40 + lg * 8];
        }
#pragma unroll
        for (int nf = 0; nf < 4; ++nf) {
            int col = wc * 64 + nf * 16 + lr;
            bh[nf]  = *(const short8*)&Bh[col * 40 + lg * 8];
            blo[nf] = *(const short8*)&Bl[col * 40 + lg * 8];
        }
#pragma unroll
        for (int mf = 0; mf < MF; ++mf)
#pragma unroll
            for (int nf = 0; nf < 4; ++nf) {
                acc[mf][nf] = __builtin_amdgcn_mfma_f32_16x16x32_bf16(ah[mf],  bh[nf],  acc[mf][nf], 0, 0, 0);
                acc[mf][nf] = __builtin_amdgcn_mfma_f32_16x16x32_bf16(ah[mf],  blo[nf], acc[mf][nf], 0, 0, 0);
                acc[mf][nf] = __builtin_amdgcn_mfma_f32_16x16x32_bf16(alo[mf], bh[nf],  acc[mf][nf], 0, 0, 0);
            }
        __syncthreads();
    }

    // ---- epilogue: zb (bf16) + el/er via in-wave reduction ----
    const int h = (bn + wc * 64) >> 6;
    float alv[4], arv[4];
#pragma unroll
    for (int nf = 0; nf < 4; ++nf) {
        alv[nf] = al[h * 64 + nf * 16 + lr];
        arv[nf] = ar[h * 64 + nf * 16 + lr];
    }
#pragma unroll
    for (int mf = 0; mf < MF; ++mf) {
#pragma unroll
        for (int j = 0; j < 4; ++j) {
            int row = bm + wr * MF * 16 + mf * 16 + lg * 4 + j;
            float sel = 0.f, ser = 0.f;
#pragma unroll
            for (int nf = 0; nf < 4; ++nf) {
                float v = acc[mf][nf][j];
                sel += v * alv[nf];
                ser += v * arv[nf];
                if (row < M)
                    zb[(size_t)row * NT + bn + wc * 64 + nf * 16 + lr] = f2bf(v);
            }
#pragma unroll
            for (int off = 1; off <= 8; off <<= 1) {
                sel += __shfl_xor(sel, off);
                ser += __shfl_xor(ser, off);
            }
            if (lr == 0 && row < M) {
                el[(size_t)row * H + h] = sel;
                er[(size_t)row * H + h] = ser;
            }
        }
    }
}

// ---------------- layer-1 aggregate: one wave per node, 4 heads merged ----------------

__global__ __launch_bounds__(256) void gat_aggregate_h4(
    const unsigned short* __restrict__ zb,   // [N,256] bf16
    const float* __restrict__ el,            // [N,4]
    const float* __restrict__ er,            // [N,4]
    const int* __restrict__ rowptr, const int* __restrict__ csr_src,
    const float* __restrict__ bias,          // [256]
    float* __restrict__ out,                 // [N,256] f32 (ELU applied)
    int Nn)
{
    __shared__ float p_lds[4][64][4];
    __shared__ int   s_lds[4][64];
    int wid = threadIdx.x >> 6;
    int lane = threadIdx.x & 63;
    int n = blockIdx.x * 4 + wid;
    if (n >= Nn) return;
    int start = rowptr[n], end = rowptr[n + 1];
    int deg = end - start;
    float4 er4 = *(const float4*)(er + (size_t)n * 4);
    int hsel = lane >> 4;

    float4 acc = make_float4(0.f, 0.f, 0.f, 0.f);
    float4 ssum = make_float4(0.f, 0.f, 0.f, 0.f);
    float m = -INFINITY;

    for (int c0 = 0; c0 < deg; c0 += 64) {
        int nc = min(64, deg - c0);
        int s_l = 0;
        float4 e4 = make_float4(-INFINITY, -INFINITY, -INFINITY, -INFINITY);
        float emax_l = -INFINITY;
        if (lane < nc) {
            s_l = csr_src[start + c0 + lane];
            float4 el4 = *(const float4*)(el + (size_t)s_l * 4);
            e4.x = el4.x + er4.x; e4.x = e4.x > 0.f ? e4.x : 0.2f * e4.x;
            e4.y = el4.y + er4.y; e4.y = e4.y > 0.f ? e4.y : 0.2f * e4.y;
            e4.z = el4.z + er4.z; e4.z = e4.z > 0.f ? e4.z : 0.2f * e4.z;
            e4.w = el4.w + er4.w; e4.w = e4.w > 0.f ? e4.w : 0.2f * e4.w;
            emax_l = fmaxf(fmaxf(e4.x, e4.y), fmaxf(e4.z, e4.w));
        }
        float cm = emax_l;
#pragma unroll
        for (int off = 32; off; off >>= 1) cm = fmaxf(cm, __shfl_xor(cm, off));
        float newm = fmaxf(m, cm);              // finite (nc >= 1)
        float scale = __expf(m - newm);         // 0 on first chunk
        ssum.x *= scale; ssum.y *= scale; ssum.z *= scale; ssum.w *= scale;
        acc.x *= scale;  acc.y *= scale;  acc.z *= scale;  acc.w *= scale;
        m = newm;
        float4 p4 = make_float4(0.f, 0.f, 0.f, 0.f);
        if (lane < nc) {
            p4.x = __expf(e4.x - m);
            p4.y = __expf(e4.y - m);
            p4.z = __expf(e4.z - m);
            p4.w = __expf(e4.w - m);
        }
        float4 cs = p4;
#pragma unroll
        for (int off = 32; off; off >>= 1) {
            cs.x += __shfl_xor(cs.x, off);
            cs.y += __shfl_xor(cs.y, off);
            cs.z += __shfl_xor(cs.z, off);
            cs.w += __shfl_xor(cs.w, off);
        }
        ssum.x += cs.x; ssum.y += cs.y; ssum.z += cs.z; ssum.w += cs.w;
        *(float4*)&p_lds[wid][lane][0] = p4;
        s_lds[wid][lane] = s_l;
#pragma unroll 2
        for (int tt = 0; tt < nc; ++tt) {
            float w = p_lds[wid][tt][hsel];
            int s = s_lds[wid][tt];
            ushort4 u = *(const ushort4*)(zb + (size_t)s * 256 + lane * 4);
            acc.x = fmaf(w, bf2f(u.x), acc.x);
            acc.y = fmaf(w, bf2f(u.y), acc.y);
            acc.z = fmaf(w, bf2f(u.z), acc.z);
            acc.w = fmaf(w, bf2f(u.w), acc.w);
        }
    }
    float s_h = hsel == 0 ? ssum.x : hsel == 1 ? ssum.y : hsel == 2 ? ssum.z : ssum.w;
    float inv = s_h > 0.f ? 1.f / s_h : 0.f;
    float4 b4 = *(const float4*)(bias + lane * 4);
    float4 o;
    o.x = acc.x * inv + b4.x; o.x = o.x > 0.f ? o.x : expm1f(o.x);
    o.y = acc.y * inv + b4.y; o.y = o.y > 0.f ? o.y : expm1f(o.y);
    o.z = acc.z * inv + b4.z; o.z = o.z > 0.f ? o.z : expm1f(o.z);
    o.w = acc.w * inv + b4.w; o.w = o.w > 0.f ? o.w : expm1f(o.w);
    *(float4*)(out + (size_t)n * 256 + lane * 4) = o;
}

// ---------------- layer-2 aggregate (H=1), bf16 gather, 4-edge groups ----------------

__global__ void gat_aggregate_bf(const unsigned short* __restrict__ zb,  // [N,64] bf16
                                 const float* __restrict__ el, const float* __restrict__ er,
                                 const int* __restrict__ rowptr, const int* __restrict__ csr_src,
                                 const float* __restrict__ bias,
                                 float* __restrict__ out, int Nn)
{
    int gw = (blockIdx.x * blockDim.x + threadIdx.x) >> 6;
    int lane = threadIdx.x & 63;
    int n = gw;
    if (n >= Nn) return;
    int start = rowptr[n], end = rowptr[n + 1];
    int deg = end - start;
    float ern = er[n];

    int group = lane >> 4;
    int gl = lane & 15;

    float4 acc = make_float4(0.f, 0.f, 0.f, 0.f);
    float m = -INFINITY;
    float ssum = 0.f;

    for (int c0 = 0; c0 < deg; c0 += 64) {
        int nc = min(64, deg - c0);
        int s_l = 0;
        float e_l = -INFINITY;
        if (lane < nc) {
            s_l = csr_src[start + c0 + lane];
            float e = el[s_l] + ern;
            e_l = e > 0.f ? e : 0.2f * e;
        }
        float cm = e_l;
#pragma unroll
        for (int off = 32; off; off >>= 1) cm = fmaxf(cm, __shfl_xor(cm, off));
        float newm = fmaxf(m, cm);
        float scale = __expf(m - newm);
        ssum *= scale;
        acc.x *= scale; acc.y *= scale; acc.z *= scale; acc.w *= scale;
        m = newm;
        float p_l = (lane < nc) ? __expf(e_l - m) : 0.f;
        float cs = p_l;
#pragma unroll
        for (int off = 32; off; off >>= 1) cs += __shfl_xor(cs, off);
        ssum += cs;
        int nIter = (nc + 3) >> 2;
        for (int i = 0; i < nIter; ++i) {
            int tt = group + 4 * i;
            float w = __shfl(p_l, tt);
            int s = __shfl(s_l, tt);
            if (tt < nc) {
                ushort4 u = *(const ushort4*)(zb + (size_t)s * 64 + gl * 4);
                acc.x = fmaf(w, bf2f(u.x), acc.x);
                acc.y = fmaf(w, bf2f(u.y), acc.y);
                acc.z = fmaf(w, bf2f(u.z), acc.z);
                acc.w = fmaf(w, bf2f(u.w), acc.w);
            }
        }
    }
#pragma unroll
    for (int off = 16; off <= 32; off <<= 1) {
        acc.x += __shfl_xor(acc.x, off);
        acc.y += __shfl_xor(acc.y, off);
        acc.z += __shfl_xor(acc.z, off);
        acc.w += __shfl_xor(acc.w, off);
    }
    float inv = ssum > 0.f ? 1.f / ssum : 0.f;
    if (lane < 16) {
        float4 o;
        o.x = acc.x * inv + bias[gl * 4 + 0];
        o.y = acc.y * inv + bias[gl * 4 + 1];
        o.z = acc.z * inv + bias[gl * 4 + 2];
        o.w = acc.w * inv + bias[gl * 4 + 3];
        *(float4*)(out + (size_t)n * 64 + gl * 4) = o;
    }
}

// ---------------- launch ----------------

static inline size_t align_up(size_t x, size_t a) { return (x + a - 1) & ~(a - 1); }

extern "C" void kernel_launch(void* const* d_in, const int* in_sizes, int n_in,
                              void* d_out, int out_size, void* d_ws, size_t ws_size,
                              hipStream_t stream) {
    const float* x   = (const float*)d_in[0];
    const float* W1  = (const float*)d_in[1];
    const float* al1 = (const float*)d_in[2];
    const float* ar1 = (const float*)d_in[3];
    const float* b1  = (const float*)d_in[4];
    const float* W2  = (const float*)d_in[5];
    const float* al2 = (const float*)d_in[6];
    const float* ar2 = (const float*)d_in[7];
    const float* b2  = (const float*)d_in[8];
    const int*   src = (const int*)d_in[9];
    const int*   dst = (const int*)d_in[10];
    float* out = (float*)d_out;

    char* ws = (char*)d_ws;
    size_t off = 0;
    unsigned short* zb1 = (unsigned short*)(ws + off); off = align_up(off + (size_t)NN * 256 * 2, 256);
    float* h1 = (float*)(ws + off); off = align_up(off + (size_t)NN * 256 * 4, 256);
    unsigned short* zb2 = (unsigned short*)(ws + off); off = align_up(off + (size_t)NN * 64 * 2, 256);
    float* el1 = (float*)(ws + off); off = align_up(off + (size_t)NN * H1 * 4, 256);
    float* er1 = (float*)(ws + off); off = align_up(off + (size_t)NN * H1 * 4, 256);
    float* el2 = (float*)(ws + off); off = align_up(off + (size_t)NN * 4, 256);
    float* er2 = (float*)(ws + off); off = align_up(off + (size_t)NN * 4, 256);
    short* W1th = (short*)(ws + off); off = align_up(off + 256 * 256 * 2, 256);
    short* W1tl = (short*)(ws + off); off = align_up(off + 256 * 256 * 2, 256);
    short* W2th = (short*)(ws + off); off = align_up(off + 64 * 256 * 2, 256);
    short* W2tl = (short*)(ws + off); off = align_up(off + 64 * 256 * 2, 256);
    int* rowptr = (int*)(ws + off); off = align_up(off + (size_t)(NN + 1) * 4, 256);
    int* deg    = (int*)(ws + off); off = align_up(off + (size_t)NN * 4, 256);
    int* fillc  = (int*)(ws + off); off = align_up(off + (size_t)NN * 4, 256);
    int* bsums  = (int*)(ws + off); off = align_up(off + 256 * 4, 256);
    int* csr_src = (int*)(ws + off); off = align_up(off + (size_t)EE * 4, 256);

    const int nScanBlocks = (NN + 255) / 256;
    const int nEdgeBlocks = (EE + 255) / 256;
    const int nMBlocks = (NN + 127) / 128;   // 391

    // CSR build + weight prep
    hipMemsetAsync(deg, 0, (size_t)NN * 4, stream);
    hipMemsetAsync(fillc, 0, (size_t)NN * 4, stream);
    wsplit<<<320, 256, 0, stream>>>(W1, W2, W1th, W1tl, W2th, W2tl);
    hist_kernel<<<nEdgeBlocks, 256, 0, stream>>>(dst, deg, EE);
    scan_block<<<nScanBlocks, 256, 0, stream>>>(deg, rowptr, bsums, NN);
    scan_bsums<<<1, 256, 0, stream>>>(bsums, nScanBlocks);
    add_offsets<<<nScanBlocks, 256, 0, stream>>>(rowptr, bsums, NN, EE);
    fill_csr<<<nEdgeBlocks, 256, 0, stream>>>(src, dst, rowptr, fillc, csr_src, EE);

    // ---- layer 1: GEMM+scores fused, then aggregate ----
    gemm_bf16x2<4, 2, 2, 256, 4><<<dim3(nMBlocks, 2), 256, 0, stream>>>(
        x, W1th, W1tl, al1, ar1, zb1, el1, er1, NN, FIN);
    gat_aggregate_h4<<<(NN + 3) / 4, 256, 0, stream>>>(
        zb1, el1, er1, rowptr, csr_src, b1, h1, NN);

    // ---- layer 2 ----
    gemm_bf16x2<2, 4, 1, 64, 1><<<dim3(nMBlocks, 1), 256, 0, stream>>>(
        h1, W2th, W2tl, al2, ar2, zb2, el2, er2, NN, H1 * HID);
    gat_aggregate_bf<<<(NN * 64 + 255) / 256, 256, 0, stream>>>(
        zb2, el2, er2, rowptr, csr_src, b2, out, NN);
}

// Round 6
// 261.566 us; speedup vs baseline: 2.6687x; 1.0753x over previous
//
#include <hip/hip_runtime.h>
#include <hip/hip_bf16.h>
#include <math.h>

#define NN 50000
#define EE 800000
#define FIN 256
#define HID 64
#define OUTD 64
#define H1 4
#define H2 1

typedef __attribute__((ext_vector_type(8))) short short8;
typedef __attribute__((ext_vector_type(4))) short short4v;
typedef __attribute__((ext_vector_type(4))) float f32x4;

// ---------------- helpers ----------------

__device__ __forceinline__ unsigned short f2bf(float f) {   // round-to-nearest-even
    unsigned u = __float_as_uint(f);
    unsigned r = (u + 0x7FFFu + ((u >> 16) & 1u)) >> 16;
    return (unsigned short)r;
}
__device__ __forceinline__ float bf2f(unsigned short u) {
    return __uint_as_float(((unsigned)u) << 16);
}

// ---------------- CSR build ----------------

__global__ void hist_kernel(const int* __restrict__ dst, int* __restrict__ deg, int nE) {
    int e = blockIdx.x * 256 + threadIdx.x;
    if (e < nE) atomicAdd(&deg[dst[e]], 1);
}

__global__ void scan_block(const int* __restrict__ in, int* __restrict__ out,
                           int* __restrict__ bsums, int n) {
    __shared__ int sh[256];
    int i = blockIdx.x * 256 + threadIdx.x;
    int v = (i < n) ? in[i] : 0;
    sh[threadIdx.x] = v;
    __syncthreads();
    for (int off = 1; off < 256; off <<= 1) {
        int t = 0;
        if (threadIdx.x >= off) t = sh[threadIdx.x - off];
        __syncthreads();
        if (threadIdx.x >= off) sh[threadIdx.x] += t;
        __syncthreads();
    }
    if (i < n) out[i] = sh[threadIdx.x] - v;          // exclusive
    if (threadIdx.x == 255) bsums[blockIdx.x] = sh[255];
}

__global__ void scan_bsums(int* __restrict__ bsums, int nb) {
    __shared__ int sh[256];
    int v = (threadIdx.x < nb) ? bsums[threadIdx.x] : 0;
    sh[threadIdx.x] = v;
    __syncthreads();
    for (int off = 1; off < 256; off <<= 1) {
        int t = 0;
        if (threadIdx.x >= off) t = sh[threadIdx.x - off];
        __syncthreads();
        if (threadIdx.x >= off) sh[threadIdx.x] += t;
        __syncthreads();
    }
    if (threadIdx.x < nb) bsums[threadIdx.x] = sh[threadIdx.x] - v;  // exclusive
}

__global__ void add_offsets(int* __restrict__ out, const int* __restrict__ bsums,
                            int n, int Etot) {
    int i = blockIdx.x * 256 + threadIdx.x;
    if (i < n) out[i] += bsums[blockIdx.x];
    if (i == 0) out[n] = Etot;
}

__global__ void fill_csr(const int* __restrict__ src, const int* __restrict__ dst,
                         const int* __restrict__ rowptr, int* __restrict__ fillc,
                         int* __restrict__ csr_src, int nE) {
    int e = blockIdx.x * 256 + threadIdx.x;
    if (e < nE) {
        int d = dst[e];
        int pos = rowptr[d] + atomicAdd(&fillc[d], 1);
        csr_src[pos] = src[e];
    }
}

// ---------------- weight prep: transpose + split f32 -> bf16 hi/lo ----------------

__global__ void wsplit(const float* __restrict__ W1, const float* __restrict__ W2,
                       short* __restrict__ W1th, short* __restrict__ W1tl,
                       short* __restrict__ W2th, short* __restrict__ W2tl) {
    int n = blockIdx.x;
    int k = threadIdx.x;
    if (n < 256) {
        float v = W1[(size_t)k * 256 + n];
        unsigned short hi = f2bf(v);
        unsigned short lo = f2bf(v - bf2f(hi));
        W1th[n * 256 + k] = (short)hi;
        W1tl[n * 256 + k] = (short)lo;
    } else {
        int n2 = n - 256;
        float v = W2[(size_t)k * 64 + n2];
        unsigned short hi = f2bf(v);
        unsigned short lo = f2bf(v - bf2f(hi));
        W2th[n2 * 256 + k] = (short)hi;
        W2tl[n2 * 256 + k] = (short)lo;
    }
}

// ---------------- MFMA GEMM + fused scores epilogue ----------
// ASPLIT=true : A f32, split to hi/lo in staging, 3 MFMA passes.
// ASPLIT=false: A already bf16 (exact), 2 MFMA passes (A*Bh + A*Bl).

template<int MF, int WR, int WC, int NT, int H, bool ASPLIT>
__global__ __launch_bounds__(256) void gemm_bf16x2(
    const void* __restrict__ Av, const short* __restrict__ Bth, const short* __restrict__ Btl,
    const float* __restrict__ al, const float* __restrict__ ar,
    unsigned short* __restrict__ zb, float* __restrict__ el, float* __restrict__ er,
    int M, int K)
{
    constexpr int BM = WR * MF * 16;   // 128
    constexpr int BN = WC * 64;
    __shared__ short Ah[128 * 40];
    __shared__ short Al[ASPLIT ? 128 * 40 : 8];
    __shared__ short Bh[BN * 40], Bl[BN * 40];

    const int bm = blockIdx.x * BM;
    const int bn = blockIdx.y * BN;
    const int t = threadIdx.x;
    const int wid = t >> 6;
    const int lane = t & 63;
    const int lr = lane & 15;
    const int lg = lane >> 4;
    const int wr = wid / WC;
    const int wc = wid % WC;

    f32x4 acc[MF][4];
#pragma unroll
    for (int mf = 0; mf < MF; ++mf)
#pragma unroll
        for (int nf = 0; nf < 4; ++nf) acc[mf][nf] = (f32x4)(0.f);

    for (int k0 = 0; k0 < K; k0 += 32) {
        if constexpr (ASPLIT) {
            const float* A = (const float*)Av;
#pragma unroll
            for (int q = 0; q < 4; ++q) {
                int linear = q * 256 + t;
                int row = linear >> 3;
                int kq = (linear & 7) * 4;
                int grow = bm + row;
                float4 av = make_float4(0.f, 0.f, 0.f, 0.f);
                if (grow < M) av = *(const float4*)(A + (size_t)grow * K + k0 + kq);
                short4v hi, lo;
                unsigned short h0 = f2bf(av.x); hi.x = (short)h0; lo.x = (short)f2bf(av.x - bf2f(h0));
                unsigned short h1v = f2bf(av.y); hi.y = (short)h1v; lo.y = (short)f2bf(av.y - bf2f(h1v));
                unsigned short h2v = f2bf(av.z); hi.z = (short)h2v; lo.z = (short)f2bf(av.z - bf2f(h2v));
                unsigned short h3v = f2bf(av.w); hi.w = (short)h3v; lo.w = (short)f2bf(av.w - bf2f(h3v));
                *(short4v*)&Ah[row * 40 + kq] = hi;
                *(short4v*)&Al[row * 40 + kq] = lo;
            }
        } else {
            const unsigned short* A = (const unsigned short*)Av;
#pragma unroll
            for (int q = 0; q < 2; ++q) {
                int linear = q * 256 + t;       // 0..511
                int row = linear >> 2;          // 0..127
                int k8 = (linear & 3) * 8;
                int grow = bm + row;
                short8 v = (short8)(0);
                if (grow < M) v = *(const short8*)(A + (size_t)grow * K + k0 + k8);
                *(short8*)&Ah[row * 40 + k8] = v;
            }
        }
#pragma unroll
        for (int q = 0; q < BN / 64; ++q) {
            int linear = q * 256 + t;
            int n = linear >> 2;
            int k8 = (linear & 3) * 8;
            short8 vh = *(const short8*)(Bth + (size_t)(bn + n) * K + k0 + k8);
            short8 vl = *(const short8*)(Btl + (size_t)(bn + n) * K + k0 + k8);
            *(short8*)&Bh[n * 40 + k8] = vh;
            *(short8*)&Bl[n * 40 + k8] = vl;
        }
        __syncthreads();

        short8 ah[MF], alo[MF], bh[4], blo[4];
#pragma unroll
        for (int mf = 0; mf < MF; ++mf) {
            int row = wr * MF * 16 + mf * 16 + lr;
            ah[mf] = *(const short8*)&Ah[row * 40 + lg * 8];
            if constexpr (ASPLIT) alo[mf] = *(const short8*)&Al[row * 40 + lg * 8];
        }
#pragma unroll
        for (int nf = 0; nf < 4; ++nf) {
            int col = wc * 64 + nf * 16 + lr;
            bh[nf]  = *(const short8*)&Bh[col * 40 + lg * 8];
            blo[nf] = *(const short8*)&Bl[col * 40 + lg * 8];
        }
#pragma unroll
        for (int mf = 0; mf < MF; ++mf)
#pragma unroll
            for (int nf = 0; nf < 4; ++nf) {
                acc[mf][nf] = __builtin_amdgcn_mfma_f32_16x16x32_bf16(ah[mf], bh[nf],  acc[mf][nf], 0, 0, 0);
                acc[mf][nf] = __builtin_amdgcn_mfma_f32_16x16x32_bf16(ah[mf], blo[nf], acc[mf][nf], 0, 0, 0);
                if constexpr (ASPLIT)
                    acc[mf][nf] = __builtin_amdgcn_mfma_f32_16x16x32_bf16(alo[mf], bh[nf], acc[mf][nf], 0, 0, 0);
            }
        __syncthreads();
    }

    // ---- epilogue: zb (bf16) + el/er ----
    const int h = (bn + wc * 64) >> 6;
    float alv[4], arv[4];
#pragma unroll
    for (int nf = 0; nf < 4; ++nf) {
        alv[nf] = al[h * 64 + nf * 16 + lr];
        arv[nf] = ar[h * 64 + nf * 16 + lr];
    }
#pragma unroll
    for (int mf = 0; mf < MF; ++mf) {
#pragma unroll
        for (int j = 0; j < 4; ++j) {
            int row = bm + wr * MF * 16 + mf * 16 + lg * 4 + j;
            float sel = 0.f, ser = 0.f;
#pragma unroll
            for (int nf = 0; nf < 4; ++nf) {
                float v = acc[mf][nf][j];
                sel += v * alv[nf];
                ser += v * arv[nf];
                if (row < M)
                    zb[(size_t)row * NT + bn + wc * 64 + nf * 16 + lr] = f2bf(v);
            }
#pragma unroll
            for (int off = 1; off <= 8; off <<= 1) {
                sel += __shfl_xor(sel, off);
                ser += __shfl_xor(ser, off);
            }
            if (lr == 0 && row < M) {
                el[(size_t)row * H + h] = sel;
                er[(size_t)row * H + h] = ser;
            }
        }
    }
}

// ---------------- layer-1 aggregate: one wave per node, 4 heads merged, batched MLP ----

__global__ __launch_bounds__(256) void gat_aggregate_h4(
    const unsigned short* __restrict__ zb,   // [N,256] bf16
    const float* __restrict__ el,            // [N,4]
    const float* __restrict__ er,            // [N,4]
    const int* __restrict__ rowptr, const int* __restrict__ csr_src,
    const float* __restrict__ bias,          // [256]
    unsigned short* __restrict__ out,        // [N,256] bf16 (ELU applied)
    int Nn)
{
    __shared__ float p_lds[4][64][4];
    __shared__ int   s_lds[4][64];
    int wid = threadIdx.x >> 6;
    int lane = threadIdx.x & 63;
    int n = blockIdx.x * 4 + wid;
    if (n >= Nn) return;
    int start = rowptr[n], end = rowptr[n + 1];
    int deg = end - start;
    float4 er4 = *(const float4*)(er + (size_t)n * 4);
    int hsel = lane >> 4;

    float4 acc = make_float4(0.f, 0.f, 0.f, 0.f);
    float4 ssum = make_float4(0.f, 0.f, 0.f, 0.f);
    float m = -INFINITY;

    for (int c0 = 0; c0 < deg; c0 += 64) {
        int nc = min(64, deg - c0);
        int s_l = 0;
        float4 e4 = make_float4(-INFINITY, -INFINITY, -INFINITY, -INFINITY);
        float emax_l = -INFINITY;
        if (lane < nc) {
            s_l = csr_src[start + c0 + lane];
            float4 el4 = *(const float4*)(el + (size_t)s_l * 4);
            e4.x = el4.x + er4.x; e4.x = e4.x > 0.f ? e4.x : 0.2f * e4.x;
            e4.y = el4.y + er4.y; e4.y = e4.y > 0.f ? e4.y : 0.2f * e4.y;
            e4.z = el4.z + er4.z; e4.z = e4.z > 0.f ? e4.z : 0.2f * e4.z;
            e4.w = el4.w + er4.w; e4.w = e4.w > 0.f ? e4.w : 0.2f * e4.w;
            emax_l = fmaxf(fmaxf(e4.x, e4.y), fmaxf(e4.z, e4.w));
        }
        float cm = emax_l;
#pragma unroll
        for (int off = 32; off; off >>= 1) cm = fmaxf(cm, __shfl_xor(cm, off));
        float newm = fmaxf(m, cm);
        float scale = __expf(m - newm);
        ssum.x *= scale; ssum.y *= scale; ssum.z *= scale; ssum.w *= scale;
        acc.x *= scale;  acc.y *= scale;  acc.z *= scale;  acc.w *= scale;
        m = newm;
        float4 p4 = make_float4(0.f, 0.f, 0.f, 0.f);
        if (lane < nc) {
            p4.x = __expf(e4.x - m);
            p4.y = __expf(e4.y - m);
            p4.z = __expf(e4.z - m);
            p4.w = __expf(e4.w - m);
        }
        float4 cs = p4;
#pragma unroll
        for (int off = 32; off; off >>= 1) {
            cs.x += __shfl_xor(cs.x, off);
            cs.y += __shfl_xor(cs.y, off);
            cs.z += __shfl_xor(cs.z, off);
            cs.w += __shfl_xor(cs.w, off);
        }
        ssum.x += cs.x; ssum.y += cs.y; ssum.z += cs.z; ssum.w += cs.w;
        *(float4*)&p_lds[wid][lane][0] = p4;
        s_lds[wid][lane] = s_l;

        // gather, batches of 8 edges: weights/srcs first, then 8 loads in flight, then FMAs
        const unsigned short* zlane = zb + lane * 4;
        for (int tt = 0; tt < nc; tt += 8) {
            float w[8]; int sv[8];
#pragma unroll
            for (int j = 0; j < 8; ++j) {
                int idx = tt + j;
                int ic = idx < nc ? idx : 0;          // valid addr, weight zeroed
                w[j] = idx < nc ? p_lds[wid][ic][hsel] : 0.f;
                sv[j] = s_lds[wid][ic];
            }
            ushort4 u[8];
#pragma unroll
            for (int j = 0; j < 8; ++j)
                u[j] = *(const ushort4*)(zlane + (size_t)sv[j] * 256);
#pragma unroll
            for (int j = 0; j < 8; ++j) {
                acc.x = fmaf(w[j], bf2f(u[j].x), acc.x);
                acc.y = fmaf(w[j], bf2f(u[j].y), acc.y);
                acc.z = fmaf(w[j], bf2f(u[j].z), acc.z);
                acc.w = fmaf(w[j], bf2f(u[j].w), acc.w);
            }
        }
    }
    float s_h = hsel == 0 ? ssum.x : hsel == 1 ? ssum.y : hsel == 2 ? ssum.z : ssum.w;
    float inv = s_h > 0.f ? 1.f / s_h : 0.f;
    float4 b4 = *(const float4*)(bias + lane * 4);
    float ox = acc.x * inv + b4.x; ox = ox > 0.f ? ox : expm1f(ox);
    float oy = acc.y * inv + b4.y; oy = oy > 0.f ? oy : expm1f(oy);
    float oz = acc.z * inv + b4.z; oz = oz > 0.f ? oz : expm1f(oz);
    float ow = acc.w * inv + b4.w; ow = ow > 0.f ? ow : expm1f(ow);
    ushort4 o;
    o.x = f2bf(ox); o.y = f2bf(oy); o.z = f2bf(oz); o.w = f2bf(ow);
    *(ushort4*)(out + (size_t)n * 256 + lane * 4) = o;
}

// ---------------- layer-2 aggregate (H=1), bf16 gather, 4-edge groups, batched ----

__global__ void gat_aggregate_bf(const unsigned short* __restrict__ zb,  // [N,64] bf16
                                 const float* __restrict__ el, const float* __restrict__ er,
                                 const int* __restrict__ rowptr, const int* __restrict__ csr_src,
                                 const float* __restrict__ bias,
                                 float* __restrict__ out, int Nn)
{
    int gw = (blockIdx.x * blockDim.x + threadIdx.x) >> 6;
    int lane = threadIdx.x & 63;
    int n = gw;
    if (n >= Nn) return;
    int start = rowptr[n], end = rowptr[n + 1];
    int deg = end - start;
    float ern = er[n];

    int group = lane >> 4;
    int gl = lane & 15;

    float4 acc = make_float4(0.f, 0.f, 0.f, 0.f);
    float m = -INFINITY;
    float ssum = 0.f;

    for (int c0 = 0; c0 < deg; c0 += 64) {
        int nc = min(64, deg - c0);
        int s_l = 0;
        float e_l = -INFINITY;
        if (lane < nc) {
            s_l = csr_src[start + c0 + lane];
            float e = el[s_l] + ern;
            e_l = e > 0.f ? e : 0.2f * e;
        }
        float cm = e_l;
#pragma unroll
        for (int off = 32; off; off >>= 1) cm = fmaxf(cm, __shfl_xor(cm, off));
        float newm = fmaxf(m, cm);
        float scale = __expf(m - newm);
        ssum *= scale;
        acc.x *= scale; acc.y *= scale; acc.z *= scale; acc.w *= scale;
        m = newm;
        float p_l = (lane < nc) ? __expf(e_l - m) : 0.f;
        float cs = p_l;
#pragma unroll
        for (int off = 32; off; off >>= 1) cs += __shfl_xor(cs, off);
        ssum += cs;

        int nIter = (nc + 3) >> 2;
        for (int i0 = 0; i0 < nIter; i0 += 4) {
            float w[4]; int sv[4];
#pragma unroll
            for (int j = 0; j < 4; ++j) {
                int tt = group + 4 * (i0 + j);
                int tc = tt & 63;
                float wv = __shfl(p_l, tc);
                int s = __shfl(s_l, tc);
                w[j] = (tt < nc) ? wv : 0.f;
                sv[j] = s;
            }
            ushort4 u[4];
#pragma unroll
            for (int j = 0; j < 4; ++j)
                u[j] = *(const ushort4*)(zb + (size_t)sv[j] * 64 + gl * 4);
#pragma unroll
            for (int j = 0; j < 4; ++j) {
                acc.x = fmaf(w[j], bf2f(u[j].x), acc.x);
                acc.y = fmaf(w[j], bf2f(u[j].y), acc.y);
                acc.z = fmaf(w[j], bf2f(u[j].z), acc.z);
                acc.w = fmaf(w[j], bf2f(u[j].w), acc.w);
            }
        }
    }
#pragma unroll
    for (int off = 16; off <= 32; off <<= 1) {
        acc.x += __shfl_xor(acc.x, off);
        acc.y += __shfl_xor(acc.y, off);
        acc.z += __shfl_xor(acc.z, off);
        acc.w += __shfl_xor(acc.w, off);
    }
    float inv = ssum > 0.f ? 1.f / ssum : 0.f;
    if (lane < 16) {
        float4 o;
        o.x = acc.x * inv + bias[gl * 4 + 0];
        o.y = acc.y * inv + bias[gl * 4 + 1];
        o.z = acc.z * inv + bias[gl * 4 + 2];
        o.w = acc.w * inv + bias[gl * 4 + 3];
        *(float4*)(out + (size_t)n * 64 + gl * 4) = o;
    }
}

// ---------------- launch ----------------

static inline size_t align_up(size_t x, size_t a) { return (x + a - 1) & ~(a - 1); }

extern "C" void kernel_launch(void* const* d_in, const int* in_sizes, int n_in,
                              void* d_out, int out_size, void* d_ws, size_t ws_size,
                              hipStream_t stream) {
    const float* x   = (const float*)d_in[0];
    const float* W1  = (const float*)d_in[1];
    const float* al1 = (const float*)d_in[2];
    const float* ar1 = (const float*)d_in[3];
    const float* b1  = (const float*)d_in[4];
    const float* W2  = (const float*)d_in[5];
    const float* al2 = (const float*)d_in[6];
    const float* ar2 = (const float*)d_in[7];
    const float* b2  = (const float*)d_in[8];
    const int*   src = (const int*)d_in[9];
    const int*   dst = (const int*)d_in[10];
    float* out = (float*)d_out;

    char* ws = (char*)d_ws;
    size_t off = 0;
    unsigned short* zb1 = (unsigned short*)(ws + off); off = align_up(off + (size_t)NN * 256 * 2, 256);
    unsigned short* h1b = (unsigned short*)(ws + off); off = align_up(off + (size_t)NN * 256 * 2, 256);
    unsigned short* zb2 = (unsigned short*)(ws + off); off = align_up(off + (size_t)NN * 64 * 2, 256);
    float* el1 = (float*)(ws + off); off = align_up(off + (size_t)NN * H1 * 4, 256);
    float* er1 = (float*)(ws + off); off = align_up(off + (size_t)NN * H1 * 4, 256);
    float* el2 = (float*)(ws + off); off = align_up(off + (size_t)NN * 4, 256);
    float* er2 = (float*)(ws + off); off = align_up(off + (size_t)NN * 4, 256);
    short* W1th = (short*)(ws + off); off = align_up(off + 256 * 256 * 2, 256);
    short* W1tl = (short*)(ws + off); off = align_up(off + 256 * 256 * 2, 256);
    short* W2th = (short*)(ws + off); off = align_up(off + 64 * 256 * 2, 256);
    short* W2tl = (short*)(ws + off); off = align_up(off + 64 * 256 * 2, 256);
    int* rowptr = (int*)(ws + off); off = align_up(off + (size_t)(NN + 1) * 4, 256);
    int* deg    = (int*)(ws + off); off = align_up(off + (size_t)NN * 4, 256);
    int* fillc  = (int*)(ws + off); off = align_up(off + (size_t)NN * 4, 256);
    int* bsums  = (int*)(ws + off); off = align_up(off + 256 * 4, 256);
    int* csr_src = (int*)(ws + off); off = align_up(off + (size_t)EE * 4, 256);

    const int nScanBlocks = (NN + 255) / 256;
    const int nEdgeBlocks = (EE + 255) / 256;
    const int nMBlocks = (NN + 127) / 128;   // 391

    hipMemsetAsync(deg, 0, (size_t)NN * 4, stream);
    hipMemsetAsync(fillc, 0, (size_t)NN * 4, stream);
    wsplit<<<320, 256, 0, stream>>>(W1, W2, W1th, W1tl, W2th, W2tl);
    hist_kernel<<<nEdgeBlocks, 256, 0, stream>>>(dst, deg, EE);
    scan_block<<<nScanBlocks, 256, 0, stream>>>(deg, rowptr, bsums, NN);
    scan_bsums<<<1, 256, 0, stream>>>(bsums, nScanBlocks);
    add_offsets<<<nScanBlocks, 256, 0, stream>>>(rowptr, bsums, NN, EE);
    fill_csr<<<nEdgeBlocks, 256, 0, stream>>>(src, dst, rowptr, fillc, csr_src, EE);

    // ---- layer 1 ----
    gemm_bf16x2<4, 2, 2, 256, 4, true><<<dim3(nMBlocks, 2), 256, 0, stream>>>(
        x, W1th, W1tl, al1, ar1, zb1, el1, er1, NN, FIN);
    gat_aggregate_h4<<<(NN + 3) / 4, 256, 0, stream>>>(
        zb1, el1, er1, rowptr, csr_src, b1, h1b, NN);

    // ---- layer 2 ----
    gemm_bf16x2<2, 4, 1, 64, 1, false><<<dim3(nMBlocks, 1), 256, 0, stream>>>(
        h1b, W2th, W2tl, al2, ar2, zb2, el2, er2, NN, H1 * HID);
    gat_aggregate_bf<<<(NN * 64 + 255) / 256, 256, 0, stream>>>(
        zb2, el2, er2, rowptr, csr_src, b2, out, NN);
}

// Round 7
// 244.357 us; speedup vs baseline: 2.8566x; 1.0704x over previous
//
#include <hip/hip_runtime.h>
#include <hip/hip_bf16.h>
#include <math.h>

#define NN 50000
#define EE 800000
#define FIN 256
#define HID 64
#define OUTD 64
#define H1 4
#define H2 1

typedef __attribute__((ext_vector_type(8))) short short8;
typedef __attribute__((ext_vector_type(4))) short short4v;
typedef __attribute__((ext_vector_type(4))) float f32x4;
typedef __attribute__((ext_vector_type(2))) float f32x2;

// ---------------- helpers ----------------

__device__ __forceinline__ unsigned short f2bf(float f) {   // round-to-nearest-even
    unsigned u = __float_as_uint(f);
    unsigned r = (u + 0x7FFFu + ((u >> 16) & 1u)) >> 16;
    return (unsigned short)r;
}
__device__ __forceinline__ float bf2f(unsigned short u) {
    return __uint_as_float(((unsigned)u) << 16);
}

// ---------------- CSR build ----------------

__global__ void hist_kernel(const int* __restrict__ dst, int* __restrict__ deg, int nE) {
    int e = blockIdx.x * 256 + threadIdx.x;
    if (e < nE) atomicAdd(&deg[dst[e]], 1);
}

__global__ void scan_block(const int* __restrict__ in, int* __restrict__ out,
                           int* __restrict__ bsums, int n) {
    __shared__ int sh[256];
    int i = blockIdx.x * 256 + threadIdx.x;
    int v = (i < n) ? in[i] : 0;
    sh[threadIdx.x] = v;
    __syncthreads();
    for (int off = 1; off < 256; off <<= 1) {
        int t = 0;
        if (threadIdx.x >= off) t = sh[threadIdx.x - off];
        __syncthreads();
        if (threadIdx.x >= off) sh[threadIdx.x] += t;
        __syncthreads();
    }
    if (i < n) out[i] = sh[threadIdx.x] - v;          // exclusive
    if (threadIdx.x == 255) bsums[blockIdx.x] = sh[255];
}

__global__ void scan_bsums(int* __restrict__ bsums, int nb) {
    __shared__ int sh[256];
    int v = (threadIdx.x < nb) ? bsums[threadIdx.x] : 0;
    sh[threadIdx.x] = v;
    __syncthreads();
    for (int off = 1; off < 256; off <<= 1) {
        int t = 0;
        if (threadIdx.x >= off) t = sh[threadIdx.x - off];
        __syncthreads();
        if (threadIdx.x >= off) sh[threadIdx.x] += t;
        __syncthreads();
    }
    if (threadIdx.x < nb) bsums[threadIdx.x] = sh[threadIdx.x] - v;  // exclusive
}

__global__ void add_offsets(int* __restrict__ out, const int* __restrict__ bsums,
                            int n, int Etot) {
    int i = blockIdx.x * 256 + threadIdx.x;
    if (i < n) out[i] += bsums[blockIdx.x];
    if (i == 0) out[n] = Etot;
}

__global__ void fill_csr(const int* __restrict__ src, const int* __restrict__ dst,
                         const int* __restrict__ rowptr, int* __restrict__ fillc,
                         int* __restrict__ csr_src, int nE) {
    int e = blockIdx.x * 256 + threadIdx.x;
    if (e < nE) {
        int d = dst[e];
        int pos = rowptr[d] + atomicAdd(&fillc[d], 1);
        csr_src[pos] = src[e];
    }
}

// ---------------- weight prep: transpose + split f32 -> bf16 hi/lo ----------------

__global__ void wsplit(const float* __restrict__ W1, const float* __restrict__ W2,
                       short* __restrict__ W1th, short* __restrict__ W1tl,
                       short* __restrict__ W2th, short* __restrict__ W2tl) {
    int n = blockIdx.x;
    int k = threadIdx.x;
    if (n < 256) {
        float v = W1[(size_t)k * 256 + n];
        unsigned short hi = f2bf(v);
        unsigned short lo = f2bf(v - bf2f(hi));
        W1th[n * 256 + k] = (short)hi;
        W1tl[n * 256 + k] = (short)lo;
    } else {
        int n2 = n - 256;
        float v = W2[(size_t)k * 64 + n2];
        unsigned short hi = f2bf(v);
        unsigned short lo = f2bf(v - bf2f(hi));
        W2th[n2 * 256 + k] = (short)hi;
        W2tl[n2 * 256 + k] = (short)lo;
    }
}

// ---------------- MFMA GEMM + fused scores epilogue ----------
// ASPLIT=true : A f32, split to hi/lo in staging, 3 MFMA passes.
// ASPLIT=false: A already bf16 (exact), 2 MFMA passes.

template<int MF, int WR, int WC, int NT, int H, bool ASPLIT>
__global__ __launch_bounds__(256) void gemm_bf16x2(
    const void* __restrict__ Av, const short* __restrict__ Bth, const short* __restrict__ Btl,
    const float* __restrict__ al, const float* __restrict__ ar,
    unsigned short* __restrict__ zb, float* __restrict__ el, float* __restrict__ er,
    int M, int K)
{
    constexpr int BM = WR * MF * 16;
    constexpr int BN = WC * 64;
    __shared__ short Ah[BM * 40];
    __shared__ short Al[ASPLIT ? BM * 40 : 8];
    __shared__ short Bh[BN * 40], Bl[BN * 40];

    const int bm = blockIdx.x * BM;
    const int bn = blockIdx.y * BN;
    const int t = threadIdx.x;
    const int wid = t >> 6;
    const int lane = t & 63;
    const int lr = lane & 15;
    const int lg = lane >> 4;
    const int wr = wid / WC;
    const int wc = wid % WC;

    f32x4 acc[MF][4];
#pragma unroll
    for (int mf = 0; mf < MF; ++mf)
#pragma unroll
        for (int nf = 0; nf < 4; ++nf) acc[mf][nf] = (f32x4)(0.f);

    for (int k0 = 0; k0 < K; k0 += 32) {
        if constexpr (ASPLIT) {
            const float* A = (const float*)Av;
#pragma unroll
            for (int q = 0; q < BM / 32; ++q) {
                int linear = q * 256 + t;
                int row = linear >> 3;
                int kq = (linear & 7) * 4;
                int grow = bm + row;
                float4 av = make_float4(0.f, 0.f, 0.f, 0.f);
                if (grow < M) av = *(const float4*)(A + (size_t)grow * K + k0 + kq);
                short4v hi, lo;
                unsigned short h0 = f2bf(av.x); hi.x = (short)h0; lo.x = (short)f2bf(av.x - bf2f(h0));
                unsigned short h1v = f2bf(av.y); hi.y = (short)h1v; lo.y = (short)f2bf(av.y - bf2f(h1v));
                unsigned short h2v = f2bf(av.z); hi.z = (short)h2v; lo.z = (short)f2bf(av.z - bf2f(h2v));
                unsigned short h3v = f2bf(av.w); hi.w = (short)h3v; lo.w = (short)f2bf(av.w - bf2f(h3v));
                *(short4v*)&Ah[row * 40 + kq] = hi;
                *(short4v*)&Al[row * 40 + kq] = lo;
            }
        } else {
            const unsigned short* A = (const unsigned short*)Av;
#pragma unroll
            for (int q = 0; q < BM / 64; ++q) {
                int linear = q * 256 + t;
                int row = linear >> 2;
                int k8 = (linear & 3) * 8;
                int grow = bm + row;
                short8 v = (short8)(0);
                if (grow < M) v = *(const short8*)(A + (size_t)grow * K + k0 + k8);
                *(short8*)&Ah[row * 40 + k8] = v;
            }
        }
#pragma unroll
        for (int q = 0; q < BN / 64; ++q) {
            int linear = q * 256 + t;
            int n = linear >> 2;
            int k8 = (linear & 3) * 8;
            short8 vh = *(const short8*)(Bth + (size_t)(bn + n) * K + k0 + k8);
            short8 vl = *(const short8*)(Btl + (size_t)(bn + n) * K + k0 + k8);
            *(short8*)&Bh[n * 40 + k8] = vh;
            *(short8*)&Bl[n * 40 + k8] = vl;
        }
        __syncthreads();

        short8 ah[MF], alo[MF], bh[4], blo[4];
#pragma unroll
        for (int mf = 0; mf < MF; ++mf) {
            int row = wr * MF * 16 + mf * 16 + lr;
            ah[mf] = *(const short8*)&Ah[row * 40 + lg * 8];
            if constexpr (ASPLIT) alo[mf] = *(const short8*)&Al[row * 40 + lg * 8];
        }
#pragma unroll
        for (int nf = 0; nf < 4; ++nf) {
            int col = wc * 64 + nf * 16 + lr;
            bh[nf]  = *(const short8*)&Bh[col * 40 + lg * 8];
            blo[nf] = *(const short8*)&Bl[col * 40 + lg * 8];
        }
#pragma unroll
        for (int mf = 0; mf < MF; ++mf)
#pragma unroll
            for (int nf = 0; nf < 4; ++nf) {
                acc[mf][nf] = __builtin_amdgcn_mfma_f32_16x16x32_bf16(ah[mf], bh[nf],  acc[mf][nf], 0, 0, 0);
                acc[mf][nf] = __builtin_amdgcn_mfma_f32_16x16x32_bf16(ah[mf], blo[nf], acc[mf][nf], 0, 0, 0);
                if constexpr (ASPLIT)
                    acc[mf][nf] = __builtin_amdgcn_mfma_f32_16x16x32_bf16(alo[mf], bh[nf], acc[mf][nf], 0, 0, 0);
            }
        __syncthreads();
    }

    // ---- epilogue: zb (bf16) + el/er ----
    const int h = (bn + wc * 64) >> 6;
    float alv[4], arv[4];
#pragma unroll
    for (int nf = 0; nf < 4; ++nf) {
        alv[nf] = al[h * 64 + nf * 16 + lr];
        arv[nf] = ar[h * 64 + nf * 16 + lr];
    }
#pragma unroll
    for (int mf = 0; mf < MF; ++mf) {
#pragma unroll
        for (int j = 0; j < 4; ++j) {
            int row = bm + wr * MF * 16 + mf * 16 + lg * 4 + j;
            float sel = 0.f, ser = 0.f;
#pragma unroll
            for (int nf = 0; nf < 4; ++nf) {
                float v = acc[mf][nf][j];
                sel += v * alv[nf];
                ser += v * arv[nf];
                if (row < M)
                    zb[(size_t)row * NT + bn + wc * 64 + nf * 16 + lr] = f2bf(v);
            }
#pragma unroll
            for (int off = 1; off <= 8; off <<= 1) {
                sel += __shfl_xor(sel, off);
                ser += __shfl_xor(ser, off);
            }
            if (lr == 0 && row < M) {
                el[(size_t)row * H + h] = sel;
                er[(size_t)row * H + h] = ser;
            }
        }
    }
}

// ---------------- layer-1 aggregate: one wave per node, 4 heads merged ----------------
// 32-bit saddr-style offsets + packed f32x2 FMA in the gather.

__global__ __launch_bounds__(256) void gat_aggregate_h4(
    const unsigned short* __restrict__ zb,   // [N,256] bf16
    const float* __restrict__ el,            // [N,4]
    const float* __restrict__ er,            // [N,4]
    const int* __restrict__ rowptr, const int* __restrict__ csr_src,
    const float* __restrict__ bias,          // [256]
    unsigned short* __restrict__ out,        // [N,256] bf16 (ELU applied)
    int Nn)
{
    __shared__ float p_lds[4][64][4];
    __shared__ int   s_lds[4][64];
    int wid = threadIdx.x >> 6;
    int lane = threadIdx.x & 63;
    int n = blockIdx.x * 4 + wid;
    if (n >= Nn) return;
    int start = rowptr[n], end = rowptr[n + 1];
    int deg = end - start;
    float4 er4 = *(const float4*)(er + (size_t)n * 4);
    int hsel = lane >> 4;
    const unsigned lb = (unsigned)(lane << 3);   // byte offset of this lane in a 512B row

    f32x2 acc01 = {0.f, 0.f}, acc23 = {0.f, 0.f};
    float4 ssum = make_float4(0.f, 0.f, 0.f, 0.f);
    float m = -INFINITY;

    for (int c0 = 0; c0 < deg; c0 += 64) {
        int nc = min(64, deg - c0);
        int s_l = 0;
        float4 e4 = make_float4(-INFINITY, -INFINITY, -INFINITY, -INFINITY);
        float emax_l = -INFINITY;
        if (lane < nc) {
            s_l = csr_src[start + c0 + lane];
            float4 el4 = *(const float4*)(el + (size_t)s_l * 4);
            e4.x = el4.x + er4.x; e4.x = e4.x > 0.f ? e4.x : 0.2f * e4.x;
            e4.y = el4.y + er4.y; e4.y = e4.y > 0.f ? e4.y : 0.2f * e4.y;
            e4.z = el4.z + er4.z; e4.z = e4.z > 0.f ? e4.z : 0.2f * e4.z;
            e4.w = el4.w + er4.w; e4.w = e4.w > 0.f ? e4.w : 0.2f * e4.w;
            emax_l = fmaxf(fmaxf(e4.x, e4.y), fmaxf(e4.z, e4.w));
        }
        float cm = emax_l;
#pragma unroll
        for (int off = 32; off; off >>= 1) cm = fmaxf(cm, __shfl_xor(cm, off));
        float newm = fmaxf(m, cm);
        float scale = __expf(m - newm);
        ssum.x *= scale; ssum.y *= scale; ssum.z *= scale; ssum.w *= scale;
        f32x2 sc2 = {scale, scale};
        acc01 *= sc2; acc23 *= sc2;
        m = newm;
        float4 p4 = make_float4(0.f, 0.f, 0.f, 0.f);
        if (lane < nc) {
            p4.x = __expf(e4.x - m);
            p4.y = __expf(e4.y - m);
            p4.z = __expf(e4.z - m);
            p4.w = __expf(e4.w - m);
        }
        float4 cs = p4;
#pragma unroll
        for (int off = 32; off; off >>= 1) {
            cs.x += __shfl_xor(cs.x, off);
            cs.y += __shfl_xor(cs.y, off);
            cs.z += __shfl_xor(cs.z, off);
            cs.w += __shfl_xor(cs.w, off);
        }
        ssum.x += cs.x; ssum.y += cs.y; ssum.z += cs.z; ssum.w += cs.w;
        *(float4*)&p_lds[wid][lane][0] = p4;
        s_lds[wid][lane] = s_l;

        // gather in batches of 8 edges: offsets+weights, 8 loads in flight, packed FMAs
        for (int tt = 0; tt < nc; tt += 8) {
            float w[8]; unsigned off32[8];
#pragma unroll
            for (int j = 0; j < 8; ++j) {
                int idx = tt + j;
                int ic = idx < nc ? idx : 0;
                w[j] = idx < nc ? p_lds[wid][ic][hsel] : 0.f;
                off32[j] = ((unsigned)s_lds[wid][ic] << 9) + lb;
            }
            uint2 u[8];
#pragma unroll
            for (int j = 0; j < 8; ++j)
                u[j] = *(const uint2*)((const char*)zb + off32[j]);
#pragma unroll
            for (int j = 0; j < 8; ++j) {
                f32x2 v01, v23, ww = {w[j], w[j]};
                v01.x = __uint_as_float(u[j].x << 16);
                v01.y = __uint_as_float(u[j].x & 0xffff0000u);
                v23.x = __uint_as_float(u[j].y << 16);
                v23.y = __uint_as_float(u[j].y & 0xffff0000u);
                acc01 = __builtin_elementwise_fma(ww, v01, acc01);
                acc23 = __builtin_elementwise_fma(ww, v23, acc23);
            }
        }
    }
    float4 acc = make_float4(acc01.x, acc01.y, acc23.x, acc23.y);
#pragma unroll
    for (int off = 16; off <= 32; off <<= 1) { }  // (no group combine needed: each lane owns its 4 channels)
    float s_h = hsel == 0 ? ssum.x : hsel == 1 ? ssum.y : hsel == 2 ? ssum.z : ssum.w;
    float inv = s_h > 0.f ? 1.f / s_h : 0.f;
    float4 b4 = *(const float4*)(bias + lane * 4);
    float ox = acc.x * inv + b4.x; ox = ox > 0.f ? ox : expm1f(ox);
    float oy = acc.y * inv + b4.y; oy = oy > 0.f ? oy : expm1f(oy);
    float oz = acc.z * inv + b4.z; oz = oz > 0.f ? oz : expm1f(oz);
    float ow = acc.w * inv + b4.w; ow = ow > 0.f ? ow : expm1f(ow);
    ushort4 o;
    o.x = f2bf(ox); o.y = f2bf(oy); o.z = f2bf(oz); o.w = f2bf(ow);
    *(ushort4*)(out + (size_t)n * 256 + lane * 4) = o;
}

// ---------------- layer-2 aggregate (H=1), bf16 gather, 4-edge groups, packed ----

__global__ void gat_aggregate_bf(const unsigned short* __restrict__ zb,  // [N,64] bf16
                                 const float* __restrict__ el, const float* __restrict__ er,
                                 const int* __restrict__ rowptr, const int* __restrict__ csr_src,
                                 const float* __restrict__ bias,
                                 float* __restrict__ out, int Nn)
{
    int gw = (blockIdx.x * blockDim.x + threadIdx.x) >> 6;
    int lane = threadIdx.x & 63;
    int n = gw;
    if (n >= Nn) return;
    int start = rowptr[n], end = rowptr[n + 1];
    int deg = end - start;
    float ern = er[n];

    int group = lane >> 4;
    int gl = lane & 15;
    const unsigned lb = (unsigned)(gl << 3);

    f32x2 acc01 = {0.f, 0.f}, acc23 = {0.f, 0.f};
    float m = -INFINITY;
    float ssum = 0.f;

    for (int c0 = 0; c0 < deg; c0 += 64) {
        int nc = min(64, deg - c0);
        int s_l = 0;
        float e_l = -INFINITY;
        if (lane < nc) {
            s_l = csr_src[start + c0 + lane];
            float e = el[s_l] + ern;
            e_l = e > 0.f ? e : 0.2f * e;
        }
        float cm = e_l;
#pragma unroll
        for (int off = 32; off; off >>= 1) cm = fmaxf(cm, __shfl_xor(cm, off));
        float newm = fmaxf(m, cm);
        float scale = __expf(m - newm);
        ssum *= scale;
        f32x2 sc2 = {scale, scale};
        acc01 *= sc2; acc23 *= sc2;
        m = newm;
        float p_l = (lane < nc) ? __expf(e_l - m) : 0.f;
        float cs = p_l;
#pragma unroll
        for (int off = 32; off; off >>= 1) cs += __shfl_xor(cs, off);
        ssum += cs;

        int nIter = (nc + 3) >> 2;
        for (int i0 = 0; i0 < nIter; i0 += 4) {
            float w[4]; unsigned off32[4];
#pragma unroll
            for (int j = 0; j < 4; ++j) {
                int tt = group + 4 * (i0 + j);
                int tc = tt & 63;
                float wv = __shfl(p_l, tc);
                int s = __shfl(s_l, tc);
                w[j] = (tt < nc) ? wv : 0.f;
                off32[j] = ((unsigned)s << 7) + lb;
            }
            uint2 u[4];
#pragma unroll
            for (int j = 0; j < 4; ++j)
                u[j] = *(const uint2*)((const char*)zb + off32[j]);
#pragma unroll
            for (int j = 0; j < 4; ++j) {
                f32x2 v01, v23, ww = {w[j], w[j]};
                v01.x = __uint_as_float(u[j].x << 16);
                v01.y = __uint_as_float(u[j].x & 0xffff0000u);
                v23.x = __uint_as_float(u[j].y << 16);
                v23.y = __uint_as_float(u[j].y & 0xffff0000u);
                acc01 = __builtin_elementwise_fma(ww, v01, acc01);
                acc23 = __builtin_elementwise_fma(ww, v23, acc23);
            }
        }
    }
    float4 acc = make_float4(acc01.x, acc01.y, acc23.x, acc23.y);
#pragma unroll
    for (int off = 16; off <= 32; off <<= 1) {
        acc.x += __shfl_xor(acc.x, off);
        acc.y += __shfl_xor(acc.y, off);
        acc.z += __shfl_xor(acc.z, off);
        acc.w += __shfl_xor(acc.w, off);
    }
    float inv = ssum > 0.f ? 1.f / ssum : 0.f;
    if (lane < 16) {
        float4 o;
        o.x = acc.x * inv + bias[gl * 4 + 0];
        o.y = acc.y * inv + bias[gl * 4 + 1];
        o.z = acc.z * inv + bias[gl * 4 + 2];
        o.w = acc.w * inv + bias[gl * 4 + 3];
        *(float4*)(out + (size_t)n * 64 + gl * 4) = o;
    }
}

// ---------------- launch ----------------

static inline size_t align_up(size_t x, size_t a) { return (x + a - 1) & ~(a - 1); }

extern "C" void kernel_launch(void* const* d_in, const int* in_sizes, int n_in,
                              void* d_out, int out_size, void* d_ws, size_t ws_size,
                              hipStream_t stream) {
    const float* x   = (const float*)d_in[0];
    const float* W1  = (const float*)d_in[1];
    const float* al1 = (const float*)d_in[2];
    const float* ar1 = (const float*)d_in[3];
    const float* b1  = (const float*)d_in[4];
    const float* W2  = (const float*)d_in[5];
    const float* al2 = (const float*)d_in[6];
    const float* ar2 = (const float*)d_in[7];
    const float* b2  = (const float*)d_in[8];
    const int*   src = (const int*)d_in[9];
    const int*   dst = (const int*)d_in[10];
    float* out = (float*)d_out;

    char* ws = (char*)d_ws;
    size_t off = 0;
    unsigned short* zb1 = (unsigned short*)(ws + off); off = align_up(off + (size_t)NN * 256 * 2, 256);
    unsigned short* h1b = (unsigned short*)(ws + off); off = align_up(off + (size_t)NN * 256 * 2, 256);
    unsigned short* zb2 = (unsigned short*)(ws + off); off = align_up(off + (size_t)NN * 64 * 2, 256);
    float* el1 = (float*)(ws + off); off = align_up(off + (size_t)NN * H1 * 4, 256);
    float* er1 = (float*)(ws + off); off = align_up(off + (size_t)NN * H1 * 4, 256);
    float* el2 = (float*)(ws + off); off = align_up(off + (size_t)NN * 4, 256);
    float* er2 = (float*)(ws + off); off = align_up(off + (size_t)NN * 4, 256);
    short* W1th = (short*)(ws + off); off = align_up(off + 256 * 256 * 2, 256);
    short* W1tl = (short*)(ws + off); off = align_up(off + 256 * 256 * 2, 256);
    short* W2th = (short*)(ws + off); off = align_up(off + 64 * 256 * 2, 256);
    short* W2tl = (short*)(ws + off); off = align_up(off + 64 * 256 * 2, 256);
    int* rowptr = (int*)(ws + off); off = align_up(off + (size_t)(NN + 1) * 4, 256);
    int* deg    = (int*)(ws + off); off = align_up(off + (size_t)NN * 4, 256);
    int* fillc  = (int*)(ws + off); off = align_up(off + (size_t)NN * 4, 256);
    int* bsums  = (int*)(ws + off); off = align_up(off + 256 * 4, 256);
    int* csr_src = (int*)(ws + off); off = align_up(off + (size_t)EE * 4, 256);

    const int nScanBlocks = (NN + 255) / 256;
    const int nEdgeBlocks = (EE + 255) / 256;
    const int nMBlocks64 = (NN + 63) / 64;     // 782
    const int nMBlocks128 = (NN + 127) / 128;  // 391

    hipMemsetAsync(deg, 0, (size_t)NN * 4, stream);
    hipMemsetAsync(fillc, 0, (size_t)NN * 4, stream);
    wsplit<<<320, 256, 0, stream>>>(W1, W2, W1th, W1tl, W2th, W2tl);
    hist_kernel<<<nEdgeBlocks, 256, 0, stream>>>(dst, deg, EE);
    scan_block<<<nScanBlocks, 256, 0, stream>>>(deg, rowptr, bsums, NN);
    scan_bsums<<<1, 256, 0, stream>>>(bsums, nScanBlocks);
    add_offsets<<<nScanBlocks, 256, 0, stream>>>(rowptr, bsums, NN, EE);
    fill_csr<<<nEdgeBlocks, 256, 0, stream>>>(src, dst, rowptr, fillc, csr_src, EE);

    // ---- layer 1: BN=256 (single A pass) ----
    gemm_bf16x2<4, 1, 4, 256, 4, true><<<dim3(nMBlocks64, 1), 256, 0, stream>>>(
        x, W1th, W1tl, al1, ar1, zb1, el1, er1, NN, FIN);
    gat_aggregate_h4<<<(NN + 3) / 4, 256, 0, stream>>>(
        zb1, el1, er1, rowptr, csr_src, b1, h1b, NN);

    // ---- layer 2 ----
    gemm_bf16x2<2, 4, 1, 64, 1, false><<<dim3(nMBlocks128, 1), 256, 0, stream>>>(
        h1b, W2th, W2tl, al2, ar2, zb2, el2, er2, NN, H1 * HID);
    gat_aggregate_bf<<<(NN * 64 + 255) / 256, 256, 0, stream>>>(
        zb2, el2, er2, rowptr, csr_src, b2, out, NN);
}